// Round 1
// baseline (924.712 us; speedup 1.0000x reference)
//
#include <hip/hip_runtime.h>

#define S_LEN 2048
#define HIDN  1024
#define NHEAD 16
#define HDIM  64
#define NBATCH 2

typedef __bf16 bf16x8 __attribute__((ext_vector_type(8)));
typedef float  f32x4  __attribute__((ext_vector_type(4)));
typedef unsigned int  u32x4 __attribute__((ext_vector_type(4)));
typedef unsigned short u16;
typedef unsigned short u16x4 __attribute__((ext_vector_type(4)));

// exp(s*0.125 + m - 8) == exp2(s*QS_L2E + m*LOG2E - 8*LOG2E)
#define LOG2E      1.4426950408889634f
#define QS_L2E     0.18033688011112042f   /* 0.125 * log2(e) */
#define NEG8_L2E  -11.541560327111707f    /* -8 * log2(e)    */

__device__ __forceinline__ u16 f2bf(float f) {
    union { float f; unsigned int u; } v; v.f = f;
    unsigned int u = v.u;
    unsigned int r = ((u >> 16) & 1u) + 0x7FFFu;
    return (u16)((u + r) >> 16);
}

__device__ __forceinline__ f32x4 mfma16(bf16x8 a, bf16x8 b, f32x4 c) {
    return __builtin_amdgcn_mfma_f32_16x16x32_bf16(a, b, c, 0, 0, 0);
}

__device__ __forceinline__ f32x4 zf4() { f32x4 z = {0.f, 0.f, 0.f, 0.f}; return z; }

// pack 8 fp32 -> 8 bf16 by truncation (v_perm grabs high halves, 1 inst / 2 elems)
__device__ __forceinline__ bf16x8 pack8_trunc(f32x4 a, f32x4 b) {
    union { f32x4 f; u32x4 u; } ua, ub;
    ua.f = a; ub.f = b;
    union { unsigned int d[4]; bf16x8 v; } r;
    r.d[0] = __builtin_amdgcn_perm(ua.u.y, ua.u.x, 0x07060302u);
    r.d[1] = __builtin_amdgcn_perm(ua.u.w, ua.u.z, 0x07060302u);
    r.d[2] = __builtin_amdgcn_perm(ub.u.y, ub.u.x, 0x07060302u);
    r.d[3] = __builtin_amdgcn_perm(ub.u.w, ub.u.z, 0x07060302u);
    return r.v;
}

// async global->LDS, 16B per lane; LDS dest must be wave-uniform base + lane*16
__device__ __forceinline__ void gld16(void* lds, const void* g) {
    __builtin_amdgcn_global_load_lds(
        (const __attribute__((address_space(1))) void*)g,
        (__attribute__((address_space(3))) void*)lds, 16, 0, 0);
}

// ---------------------------------------------------------------------------
// Kernel 0: fp32 -> bf16 convert (n % 1024 == 0)
// ---------------------------------------------------------------------------
__global__ __launch_bounds__(256) void cvt_bf16(
    const float* __restrict__ s, u16* __restrict__ d, int n)
{
    int i = (blockIdx.x * 256 + threadIdx.x) * 4;
    if (i >= n) return;
    float4 v = *(const float4*)&s[i];
    u16x4 o = { f2bf(v.x), f2bf(v.y), f2bf(v.z), f2bf(v.w) };
    *(u16x4*)&d[i] = o;
}

// ---------------------------------------------------------------------------
// Kernel 1: QKV projection, bf16 in/out.  out = hsb @ W^T + bias
// M=4096, N=1024, K=1024.  128x128 tile, BK=32, global_load_lds staging.
// z=0 -> Qf row-major, z=1 -> Kf row-major, z=2 -> Vt[b][h][d][s].
// ---------------------------------------------------------------------------
__global__ __launch_bounds__(256) void qkv_gemm(
    const u16* __restrict__ hsb,
    const u16* __restrict__ Wqb, const u16* __restrict__ Wkb, const u16* __restrict__ Wvb,
    const float* __restrict__ bq, const float* __restrict__ bk, const float* __restrict__ bv,
    u16* __restrict__ Qf, u16* __restrict__ Kf, u16* __restrict__ Vt)
{
    __shared__ u16 As[128 * 32];
    __shared__ u16 Bs[128 * 32];

    const int z = blockIdx.z;
    const u16*   __restrict__ W    = (z == 0) ? Wqb : (z == 1) ? Wkb : Wvb;
    const float* __restrict__ bias = (z == 0) ? bq  : (z == 1) ? bk  : bv;

    const int mbase = blockIdx.x * 128;
    const int nbase = blockIdx.y * 128;
    const int tid  = threadIdx.x;
    const int lane = tid & 63;
    const int wv   = tid >> 6;
    const int wrow = wv >> 1, wcol = wv & 1;
    const int lrow = lane & 15, quad = lane >> 4;

    // staging chunk ids: c and c+256; row = c>>2, ushort col offset = (c&3)*8
    const int c0 = tid, c1 = tid + 256;
    const int r0 = c0 >> 2, o0 = (c0 & 3) * 8;
    const int r1 = c1 >> 2, o1 = (c1 & 3) * 8;
    const u16* a0p = &hsb[(size_t)(mbase + r0) * HIDN + o0];
    const u16* a1p = &hsb[(size_t)(mbase + r1) * HIDN + o1];
    const u16* b0p = &W  [(size_t)(nbase + r0) * HIDN + o0];
    const u16* b1p = &W  [(size_t)(nbase + r1) * HIDN + o1];

    f32x4 acc[4][4];
#pragma unroll
    for (int i = 0; i < 4; ++i)
#pragma unroll
        for (int j = 0; j < 4; ++j) acc[i][j] = zf4();

    for (int k0 = 0; k0 < HIDN; k0 += 32) {
        gld16(&As[c0 * 8], a0p + k0);
        gld16(&As[c1 * 8], a1p + k0);
        gld16(&Bs[c0 * 8], b0p + k0);
        gld16(&Bs[c1 * 8], b1p + k0);
        __syncthreads();   // drains vmcnt -> staged tile visible

        bf16x8 af[4], bfr[4];
#pragma unroll
        for (int i = 0; i < 4; ++i)
            af[i] = *(const bf16x8*)&As[(wrow * 64 + i * 16 + lrow) * 32 + quad * 8];
#pragma unroll
        for (int j = 0; j < 4; ++j)
            bfr[j] = *(const bf16x8*)&Bs[(wcol * 64 + j * 16 + lrow) * 32 + quad * 8];
#pragma unroll
        for (int i = 0; i < 4; ++i)
#pragma unroll
            for (int j = 0; j < 4; ++j)
                acc[i][j] = mfma16(af[i], bfr[j], acc[i][j]);
        __syncthreads();   // protect LDS before next staging overwrite
    }

    // epilogue: C/D layout row = quad*4+reg, col = lrow
    if (z == 2) {
        const int bb = mbase >> 11;           // batch (uniform per block)
        const int sb = mbase & 2047;
#pragma unroll
        for (int i = 0; i < 4; ++i) {
#pragma unroll
            for (int j = 0; j < 4; ++j) {
                const int n = nbase + wcol * 64 + j * 16 + lrow;
                const int hh = n >> 6, d = n & 63;
                const float bs = bias[n];
                const int sbase = sb + wrow * 64 + i * 16 + quad * 4;
                u16x4 pk = { f2bf(acc[i][j][0] + bs), f2bf(acc[i][j][1] + bs),
                             f2bf(acc[i][j][2] + bs), f2bf(acc[i][j][3] + bs) };
                *(u16x4*)&Vt[(((size_t)(bb * NHEAD + hh)) * HDIM + d) * S_LEN + sbase] = pk;
            }
        }
    } else {
        u16* __restrict__ O = (z == 0) ? Qf : Kf;
#pragma unroll
        for (int i = 0; i < 4; ++i) {
#pragma unroll
            for (int j = 0; j < 4; ++j) {
                const int n = nbase + wcol * 64 + j * 16 + lrow;
                const float bs = bias[n];
#pragma unroll
                for (int reg = 0; reg < 4; ++reg) {
                    const int m = mbase + wrow * 64 + i * 16 + quad * 4 + reg;
                    O[(size_t)m * HIDN + n] = f2bf(acc[i][j][reg] + bs);
                }
            }
        }
    }
}

// ---------------------------------------------------------------------------
// Kernel 2: causal attention — RESTRUCTURED.
// Block = (b, h, 64-row q-strip), grid (32,16,2). Each of the 4 waves OWNS
// 16 q-rows and loops over ALL kt tiles (0..qt). All 4 waves stream the same
// K/V tile at the same iteration -> L1-served (16KB/tile), 4x less L2 traffic
// vs the previous kt-split. No cross-wave state: no barriers, no ctx-combine
// LDS, no cross-wave l reduction. LDS 33.7KB -> 16KB (pfl only): 8 blocks/CU.
// exp folded to a single exp2f(fmaf(...)) (v_exp_f32 is natively 2^x).
// Pass 1: l = sum exp2(...). Pass 2: recompute scores, stage P fp32 in LDS
// (wave-private, same-wave write->read needs only lgkmcnt), store probs as
// float4 (256B segments), build PV bf16 A-frag via v_perm truncation pack,
// accumulate ctx and store directly (64B coalesced segments per quad).
// Only the diagonal tile (kt==qt) does the causal compare.
// ---------------------------------------------------------------------------
__global__ __launch_bounds__(256) void attn_kernel(
    const u16* __restrict__ Qf,
    const u16* __restrict__ Kf,
    const u16* __restrict__ Vt,
    const float* __restrict__ amask,
    float* __restrict__ ctx,
    float* __restrict__ probs)
{
    const int qt = 31 - blockIdx.x;      // 64-row strip; heavy strips first
    const int h  = blockIdx.y;
    const int b  = blockIdx.z;
    const int bh = b * NHEAD + h;
    const int tid  = threadIdx.x;
    const int lane = tid & 63;
    const int wv   = tid >> 6;
    const int lrow = lane & 15, quad = lane >> 4;
    const int nkt  = qt + 1;             // # of 64-col tiles touching causal region
    const int row0 = qt * 64 + wv * 16;  // this wave's q-row base

    __shared__ float pfl[4][16 * 64];    // wave-private fp32 P staging (C layout)

    // ---- zero-fill fully-masked probs tail (cols >= nkt*64), 64 rows ----
    {
        const int tail = nkt * 64;
        const int nt4  = (S_LEN - tail) >> 2;
        const int r  = tid >> 2;         // 4 threads per row, 64 rows
        const int c0 = tid & 3;
        const f32x4 zf = {0.f, 0.f, 0.f, 0.f};
        float* pr = &probs[((size_t)bh * S_LEN + qt * 64 + r) * S_LEN + tail];
        for (int c4 = c0; c4 < nt4; c4 += 4)
            __builtin_nontemporal_store(zf, (f32x4*)&pr[c4 * 4]);
    }

    // ---- Q fragments (wave's own 16 rows) ----
    const u16* qp = &Qf[((size_t)b * S_LEN + row0 + lrow) * HIDN + h * HDIM + quad * 8];
    const bf16x8 qa0 = *(const bf16x8*)qp;
    const bf16x8 qa1 = *(const bf16x8*)(qp + 32);

    const float* __restrict__ am = &amask[(size_t)b * S_LEN];
    const u16* __restrict__ kbase = &Kf[(size_t)b * S_LEN * HIDN + h * HDIM + quad * 8];

    // ---- pass 1: denominators (intra-wave only) ----
    float l_lane[4] = {0.f, 0.f, 0.f, 0.f};
    for (int kt = 0; kt < nkt; ++kt) {
        f32x4 c[4];
#pragma unroll
        for (int cb = 0; cb < 4; ++cb) {
            const int col = kt * 64 + cb * 16 + lrow;
            const u16* kp = kbase + (size_t)col * HIDN;
            bf16x8 kb0 = *(const bf16x8*)kp;
            bf16x8 kb1 = *(const bf16x8*)(kp + 32);
            c[cb] = mfma16(qa0, kb0, zf4());
            c[cb] = mfma16(qa1, kb1, c[cb]);
        }
        if (kt == qt) {   // diagonal tile: causal compare
#pragma unroll
            for (int cb = 0; cb < 4; ++cb) {
                const int col = kt * 64 + cb * 16 + lrow;
                const float m8 = fmaf(am[col], LOG2E, NEG8_L2E);
#pragma unroll
                for (int reg = 0; reg < 4; ++reg) {
                    const int row = row0 + quad * 4 + reg;
                    const float e = exp2f(fmaf(c[cb][reg], QS_L2E, m8));
                    l_lane[reg] += (col <= row) ? e : 0.f;
                }
            }
        } else {           // interior: always unmasked
#pragma unroll
            for (int cb = 0; cb < 4; ++cb) {
                const int col = kt * 64 + cb * 16 + lrow;
                const float m8 = fmaf(am[col], LOG2E, NEG8_L2E);
#pragma unroll
                for (int reg = 0; reg < 4; ++reg)
                    l_lane[reg] += exp2f(fmaf(c[cb][reg], QS_L2E, m8));
            }
        }
    }
    // row-sum over the 16 lrow lanes (width-16 butterfly); no cross-wave combine
    float inv_l[4];
#pragma unroll
    for (int reg = 0; reg < 4; ++reg) {
#pragma unroll
        for (int off = 1; off < 16; off <<= 1)
            l_lane[reg] += __shfl_xor(l_lane[reg], off, 16);
        inv_l[reg] = 1.f / l_lane[reg];
    }

    // ---- pass 2: probs + ctx ----
    f32x4 av[4];
#pragma unroll
    for (int db = 0; db < 4; ++db) av[db] = zf4();

    float* __restrict__ pw = pfl[wv];
    const u16* __restrict__ vbase = &Vt[(size_t)bh * HDIM * S_LEN + quad * 8];

    for (int kt = 0; kt < nkt; ++kt) {
        f32x4 c[4];
#pragma unroll
        for (int cb = 0; cb < 4; ++cb) {
            const int col = kt * 64 + cb * 16 + lrow;
            const u16* kp = kbase + (size_t)col * HIDN;
            bf16x8 kb0 = *(const bf16x8*)kp;
            bf16x8 kb1 = *(const bf16x8*)(kp + 32);
            c[cb] = mfma16(qa0, kb0, zf4());
            c[cb] = mfma16(qa1, kb1, c[cb]);
        }
        if (kt == qt) {
#pragma unroll
            for (int cb = 0; cb < 4; ++cb) {
                const int col = kt * 64 + cb * 16 + lrow;
                const float m8 = fmaf(am[col], LOG2E, NEG8_L2E);
#pragma unroll
                for (int reg = 0; reg < 4; ++reg) {
                    const int row = row0 + quad * 4 + reg;
                    const float p = (col <= row)
                        ? exp2f(fmaf(c[cb][reg], QS_L2E, m8)) * inv_l[reg] : 0.f;
                    pw[(quad * 4 + reg) * 64 + cb * 16 + lrow] = p;
                }
            }
        } else {
#pragma unroll
            for (int cb = 0; cb < 4; ++cb) {
                const int col = kt * 64 + cb * 16 + lrow;
                const float m8 = fmaf(am[col], LOG2E, NEG8_L2E);
#pragma unroll
                for (int reg = 0; reg < 4; ++reg) {
                    const float p = exp2f(fmaf(c[cb][reg], QS_L2E, m8)) * inv_l[reg];
                    pw[(quad * 4 + reg) * 64 + cb * 16 + lrow] = p;
                }
            }
        }
        // same-wave LDS write->read: compiler inserts lgkmcnt wait, no barrier

        // probs store: float4 lanes, 4 insts/tile, 256B contiguous segments
#pragma unroll
        for (int it = 0; it < 4; ++it) {
            const int r = it * 4 + quad;
            f32x4 v = *(const f32x4*)&pw[r * 64 + lrow * 4];
            __builtin_nontemporal_store(
                v, (f32x4*)&probs[((size_t)bh * S_LEN + row0 + r) * S_LEN + kt * 64 + lrow * 4]);
        }

        // PV A-fragment from fp32 LDS, truncation-packed to bf16
        f32x4 p0 = *(const f32x4*)&pw[lrow * 64 + quad * 8];
        f32x4 p1 = *(const f32x4*)&pw[lrow * 64 + quad * 8 + 4];
        f32x4 p2 = *(const f32x4*)&pw[lrow * 64 + 32 + quad * 8];
        f32x4 p3 = *(const f32x4*)&pw[lrow * 64 + 32 + quad * 8 + 4];
        bf16x8 pa0 = pack8_trunc(p0, p1);
        bf16x8 pa1 = pack8_trunc(p2, p3);
#pragma unroll
        for (int db = 0; db < 4; ++db) {
            const u16* vp = vbase + (size_t)(db * 16 + lrow) * S_LEN + kt * 64;
            bf16x8 vb0 = *(const bf16x8*)vp;
            bf16x8 vb1 = *(const bf16x8*)(vp + 32);
            av[db] = mfma16(pa0, vb0, av[db]);
            av[db] = mfma16(pa1, vb1, av[db]);
        }
    }

    // ---- ctx store, direct from accumulators (no cross-wave combine) ----
    // av[db][reg] = ctx[row0 + quad*4 + reg][h*64 + db*16 + lrow]
#pragma unroll
    for (int db = 0; db < 4; ++db) {
#pragma unroll
        for (int reg = 0; reg < 4; ++reg) {
            __builtin_nontemporal_store(
                av[db][reg],
                &ctx[((size_t)b * S_LEN + row0 + quad * 4 + reg) * HIDN
                     + h * HDIM + db * 16 + lrow]);
        }
    }
}

// ---------------------------------------------------------------------------
extern "C" void kernel_launch(void* const* d_in, const int* in_sizes, int n_in,
                              void* d_out, int out_size, void* d_ws, size_t ws_size,
                              hipStream_t stream)
{
    const float* hs    = (const float*)d_in[0];
    const float* amask = (const float*)d_in[1];
    const float* Wq    = (const float*)d_in[2];
    const float* bq    = (const float*)d_in[3];
    const float* Wk    = (const float*)d_in[4];
    const float* bk    = (const float*)d_in[5];
    const float* Wv    = (const float*)d_in[6];
    const float* bv    = (const float*)d_in[7];

    float* out   = (float*)d_out;
    float* ctx   = out;                                     // [2,2048,1024]
    float* probs = out + (size_t)NBATCH * S_LEN * HIDN;     // [2,16,2048,2048]

    const size_t NTOK = (size_t)NBATCH * S_LEN;             // 4096
    u16* hsb = (u16*)d_ws;                                  // bf16 [4096][1024]
    u16* Wqb = hsb + NTOK * HIDN;                           // bf16 [1024][1024]
    u16* Wkb = Wqb + (size_t)HIDN * HIDN;
    u16* Wvb = Wkb + (size_t)HIDN * HIDN;
    u16* Qf  = Wvb + (size_t)HIDN * HIDN;                   // bf16 [4096][1024]
    u16* Kf  = Qf + NTOK * HIDN;
    u16* Vt  = Kf + NTOK * HIDN;                            // bf16 [B][NH][64][2048]

    const int n_hs = (int)(NTOK * HIDN);
    const int n_w  = HIDN * HIDN;
    cvt_bf16<<<n_hs / 1024, 256, 0, stream>>>(hs, hsb, n_hs);
    cvt_bf16<<<n_w  / 1024, 256, 0, stream>>>(Wq, Wqb, n_w);
    cvt_bf16<<<n_w  / 1024, 256, 0, stream>>>(Wk, Wkb, n_w);
    cvt_bf16<<<n_w  / 1024, 256, 0, stream>>>(Wv, Wvb, n_w);

    qkv_gemm<<<dim3(32, 8, 3), 256, 0, stream>>>(hsb, Wqb, Wkb, Wvb, bq, bk, bv, Qf, Kf, Vt);
    attn_kernel<<<dim3(32, 16, 2), 256, 0, stream>>>(Qf, Kf, Vt, amask, ctx, probs);
}

// Round 2
// 778.872 us; speedup vs baseline: 1.1872x; 1.1872x over previous
//
#include <hip/hip_runtime.h>

#define S_LEN 2048
#define HIDN  1024
#define NHEAD 16
#define HDIM  64
#define NBATCH 2

typedef __bf16 bf16x8 __attribute__((ext_vector_type(8)));
typedef float  f32x4  __attribute__((ext_vector_type(4)));
typedef unsigned int  u32x4 __attribute__((ext_vector_type(4)));
typedef unsigned short u16;
typedef unsigned short u16x4 __attribute__((ext_vector_type(4)));

// exp(s*0.125 + m - 8) == exp2(s*QS_L2E + m*LOG2E - 8*LOG2E)
#define LOG2E      1.4426950408889634f
#define QS_L2E     0.18033688011112042f   /* 0.125 * log2(e) */
#define NEG8_L2E  -11.541560327111707f    /* -8 * log2(e)    */

#define PSTR 68   /* pfl leading-dim pad: 16B-aligned, 2-way banks on all 3 access patterns */

__device__ __forceinline__ u16 f2bf(float f) {
    union { float f; unsigned int u; } v; v.f = f;
    unsigned int u = v.u;
    unsigned int r = ((u >> 16) & 1u) + 0x7FFFu;
    return (u16)((u + r) >> 16);
}

__device__ __forceinline__ f32x4 mfma16(bf16x8 a, bf16x8 b, f32x4 c) {
    return __builtin_amdgcn_mfma_f32_16x16x32_bf16(a, b, c, 0, 0, 0);
}

__device__ __forceinline__ f32x4 zf4() { f32x4 z = {0.f, 0.f, 0.f, 0.f}; return z; }

// pack 8 fp32 -> 8 bf16 by truncation (v_perm grabs high halves, 1 inst / 2 elems)
__device__ __forceinline__ bf16x8 pack8_trunc(f32x4 a, f32x4 b) {
    union { f32x4 f; u32x4 u; } ua, ub;
    ua.f = a; ub.f = b;
    union { unsigned int d[4]; bf16x8 v; } r;
    r.d[0] = __builtin_amdgcn_perm(ua.u.y, ua.u.x, 0x07060302u);
    r.d[1] = __builtin_amdgcn_perm(ua.u.w, ua.u.z, 0x07060302u);
    r.d[2] = __builtin_amdgcn_perm(ub.u.y, ub.u.x, 0x07060302u);
    r.d[3] = __builtin_amdgcn_perm(ub.u.w, ub.u.z, 0x07060302u);
    return r.v;
}

// async global->LDS, 16B per lane; LDS dest must be wave-uniform base + lane*16
__device__ __forceinline__ void gld16(void* lds, const void* g) {
    __builtin_amdgcn_global_load_lds(
        (const __attribute__((address_space(1))) void*)g,
        (__attribute__((address_space(3))) void*)lds, 16, 0, 0);
}

// ---------------------------------------------------------------------------
// Kernel 0: fp32 -> bf16 convert (n % 1024 == 0)
// ---------------------------------------------------------------------------
__global__ __launch_bounds__(256) void cvt_bf16(
    const float* __restrict__ s, u16* __restrict__ d, int n)
{
    int i = (blockIdx.x * 256 + threadIdx.x) * 4;
    if (i >= n) return;
    float4 v = *(const float4*)&s[i];
    u16x4 o = { f2bf(v.x), f2bf(v.y), f2bf(v.z), f2bf(v.w) };
    *(u16x4*)&d[i] = o;
}

// ---------------------------------------------------------------------------
// Kernel 1: QKV projection, bf16 in/out.  out = hsb @ W^T + bias
// M=4096, N=1024, K=1024.  128x128 tile, BK=32, global_load_lds staging.
// z=0 -> Qf row-major, z=1 -> Kf row-major, z=2 -> Vt[b][h][d][s].
// ---------------------------------------------------------------------------
__global__ __launch_bounds__(256) void qkv_gemm(
    const u16* __restrict__ hsb,
    const u16* __restrict__ Wqb, const u16* __restrict__ Wkb, const u16* __restrict__ Wvb,
    const float* __restrict__ bq, const float* __restrict__ bk, const float* __restrict__ bv,
    u16* __restrict__ Qf, u16* __restrict__ Kf, u16* __restrict__ Vt)
{
    __shared__ u16 As[128 * 32];
    __shared__ u16 Bs[128 * 32];

    const int z = blockIdx.z;
    const u16*   __restrict__ W    = (z == 0) ? Wqb : (z == 1) ? Wkb : Wvb;
    const float* __restrict__ bias = (z == 0) ? bq  : (z == 1) ? bk  : bv;

    const int mbase = blockIdx.x * 128;
    const int nbase = blockIdx.y * 128;
    const int tid  = threadIdx.x;
    const int lane = tid & 63;
    const int wv   = tid >> 6;
    const int wrow = wv >> 1, wcol = wv & 1;
    const int lrow = lane & 15, quad = lane >> 4;

    // staging chunk ids: c and c+256; row = c>>2, ushort col offset = (c&3)*8
    const int c0 = tid, c1 = tid + 256;
    const int r0 = c0 >> 2, o0 = (c0 & 3) * 8;
    const int r1 = c1 >> 2, o1 = (c1 & 3) * 8;
    const u16* a0p = &hsb[(size_t)(mbase + r0) * HIDN + o0];
    const u16* a1p = &hsb[(size_t)(mbase + r1) * HIDN + o1];
    const u16* b0p = &W  [(size_t)(nbase + r0) * HIDN + o0];
    const u16* b1p = &W  [(size_t)(nbase + r1) * HIDN + o1];

    f32x4 acc[4][4];
#pragma unroll
    for (int i = 0; i < 4; ++i)
#pragma unroll
        for (int j = 0; j < 4; ++j) acc[i][j] = zf4();

    for (int k0 = 0; k0 < HIDN; k0 += 32) {
        gld16(&As[c0 * 8], a0p + k0);
        gld16(&As[c1 * 8], a1p + k0);
        gld16(&Bs[c0 * 8], b0p + k0);
        gld16(&Bs[c1 * 8], b1p + k0);
        __syncthreads();   // drains vmcnt -> staged tile visible

        bf16x8 af[4], bfr[4];
#pragma unroll
        for (int i = 0; i < 4; ++i)
            af[i] = *(const bf16x8*)&As[(wrow * 64 + i * 16 + lrow) * 32 + quad * 8];
#pragma unroll
        for (int j = 0; j < 4; ++j)
            bfr[j] = *(const bf16x8*)&Bs[(wcol * 64 + j * 16 + lrow) * 32 + quad * 8];
#pragma unroll
        for (int i = 0; i < 4; ++i)
#pragma unroll
            for (int j = 0; j < 4; ++j)
                acc[i][j] = mfma16(af[i], bfr[j], acc[i][j]);
        __syncthreads();   // protect LDS before next staging overwrite
    }

    // epilogue: C/D layout row = quad*4+reg, col = lrow
    if (z == 2) {
        const int bb = mbase >> 11;           // batch (uniform per block)
        const int sb = mbase & 2047;
#pragma unroll
        for (int i = 0; i < 4; ++i) {
#pragma unroll
            for (int j = 0; j < 4; ++j) {
                const int n = nbase + wcol * 64 + j * 16 + lrow;
                const int hh = n >> 6, d = n & 63;
                const float bs = bias[n];
                const int sbase = sb + wrow * 64 + i * 16 + quad * 4;
                u16x4 pk = { f2bf(acc[i][j][0] + bs), f2bf(acc[i][j][1] + bs),
                             f2bf(acc[i][j][2] + bs), f2bf(acc[i][j][3] + bs) };
                *(u16x4*)&Vt[(((size_t)(bb * NHEAD + hh)) * HDIM + d) * S_LEN + sbase] = pk;
            }
        }
    } else {
        u16* __restrict__ O = (z == 0) ? Qf : Kf;
#pragma unroll
        for (int i = 0; i < 4; ++i) {
#pragma unroll
            for (int j = 0; j < 4; ++j) {
                const int n = nbase + wcol * 64 + j * 16 + lrow;
                const float bs = bias[n];
#pragma unroll
                for (int reg = 0; reg < 4; ++reg) {
                    const int m = mbase + wrow * 64 + i * 16 + quad * 4 + reg;
                    O[(size_t)m * HIDN + n] = f2bf(acc[i][j][reg] + bs);
                }
            }
        }
    }
}

// ---------------------------------------------------------------------------
// Kernel 2: causal attention. Block = (b, h, 16-row q-tile), grid (128,16,2)
// = 4096 blocks (16 per CU available). 4 waves split the kt (64-col) tiles.
// vs round-1 (425us, Occ 28%, latency-bound): back to the high-parallelism
// kt-split, but with the two round-0 defects fixed:
//  - LDS 33.8KB -> 17.7KB: ctx combine OVERLAYS pfl (own-wave overwrite is
//    race-free; cross-wave reads only after the barrier). 8 blocks/CU,
//    100% wave occupancy (VGPR 56 <= 64).
//  - pfl stride 64 -> 68 floats: P-writes, PV b128 transpose reads and probs
//    f32x4 reads all resolve to <=2 lanes/bank (was up to 16-way).
// exp folded to one v_exp_f32 via exp2 constants.
// ---------------------------------------------------------------------------
__global__ __launch_bounds__(256) void attn_kernel(
    const u16* __restrict__ Qf,
    const u16* __restrict__ Kf,
    const u16* __restrict__ Vt,
    const float* __restrict__ amask,
    float* __restrict__ ctx,
    float* __restrict__ probs)
{
    const int qt = 127 - blockIdx.x;     // heavy blocks dispatch first
    const int h  = blockIdx.y;
    const int b  = blockIdx.z;
    const int bh = b * NHEAD + h;
    const int tid  = threadIdx.x;
    const int lane = tid & 63;
    const int wv   = tid >> 6;
    const int lrow = lane & 15, quad = lane >> 4;
    const int row0 = qt * 16;
    const int dti  = qt >> 2;            // diagonal tile index
    const int nkt  = dti + 1;            // # of 64-col tiles touching causal region

    __shared__ float pfl[4][16 * PSTR];  // wave-private fp32 P staging; combine overlay
    __shared__ float l_sh[4][16];

    // ---- zero-fill fully-masked probs tail (cols >= nkt*64) ----
    {
        const int tail  = nkt * 64;
        const int nt4   = (S_LEN - tail) >> 2;
        const int r  = tid >> 4;         // 16 threads per row
        const int c0 = tid & 15;
        const f32x4 zf = {0.f, 0.f, 0.f, 0.f};
        float* pr = &probs[((size_t)bh * S_LEN + row0 + r) * S_LEN + tail];
        for (int c4 = c0; c4 < nt4; c4 += 16)
            __builtin_nontemporal_store(zf, (f32x4*)&pr[c4 * 4]);
    }

    // ---- Q fragments ----
    const u16* qp = &Qf[((size_t)b * S_LEN + row0 + lrow) * HIDN + h * HDIM + quad * 8];
    const bf16x8 qa0 = *(const bf16x8*)qp;
    const bf16x8 qa1 = *(const bf16x8*)(qp + 32);

    const float* __restrict__ am = &amask[(size_t)b * S_LEN];
    const u16* __restrict__ kbase = &Kf[(size_t)b * S_LEN * HIDN + h * HDIM + quad * 8];

    // ---- pass 1: denominators ----
    float l_lane[4] = {0.f, 0.f, 0.f, 0.f};
    for (int kt = wv; kt < nkt; kt += 4) {
        f32x4 c[4];
#pragma unroll
        for (int cb = 0; cb < 4; ++cb) {
            const int col = kt * 64 + cb * 16 + lrow;
            const u16* kp = kbase + (size_t)col * HIDN;
            bf16x8 kb0 = *(const bf16x8*)kp;
            bf16x8 kb1 = *(const bf16x8*)(kp + 32);
            c[cb] = mfma16(qa0, kb0, zf4());
            c[cb] = mfma16(qa1, kb1, c[cb]);
        }
        if (kt == dti) {   // diagonal tile: causal compare
#pragma unroll
            for (int cb = 0; cb < 4; ++cb) {
                const int col = kt * 64 + cb * 16 + lrow;
                const float m8 = fmaf(am[col], LOG2E, NEG8_L2E);
#pragma unroll
                for (int reg = 0; reg < 4; ++reg) {
                    const int row = row0 + quad * 4 + reg;
                    const float e = exp2f(fmaf(c[cb][reg], QS_L2E, m8));
                    l_lane[reg] += (col <= row) ? e : 0.f;
                }
            }
        } else {           // interior: always unmasked
#pragma unroll
            for (int cb = 0; cb < 4; ++cb) {
                const int col = kt * 64 + cb * 16 + lrow;
                const float m8 = fmaf(am[col], LOG2E, NEG8_L2E);
#pragma unroll
                for (int reg = 0; reg < 4; ++reg)
                    l_lane[reg] += exp2f(fmaf(c[cb][reg], QS_L2E, m8));
            }
        }
    }
#pragma unroll
    for (int reg = 0; reg < 4; ++reg) {
#pragma unroll
        for (int off = 1; off < 16; off <<= 1)
            l_lane[reg] += __shfl_xor(l_lane[reg], off, 16);
    }
    if (lrow == 0) {
#pragma unroll
        for (int reg = 0; reg < 4; ++reg)
            l_sh[wv][quad * 4 + reg] = l_lane[reg];
    }
    __syncthreads();
    float inv_l[4];
#pragma unroll
    for (int reg = 0; reg < 4; ++reg) {
        const int rr = quad * 4 + reg;
        inv_l[reg] = 1.f / (l_sh[0][rr] + l_sh[1][rr] + l_sh[2][rr] + l_sh[3][rr]);
    }

    // ---- pass 2: probs + ctx partials ----
    f32x4 av[4];
#pragma unroll
    for (int db = 0; db < 4; ++db) av[db] = zf4();

    float* __restrict__ pw = pfl[wv];
    const u16* __restrict__ vbase = &Vt[(size_t)bh * HDIM * S_LEN + quad * 8];

    for (int kt = wv; kt < nkt; kt += 4) {
        f32x4 c[4];
#pragma unroll
        for (int cb = 0; cb < 4; ++cb) {
            const int col = kt * 64 + cb * 16 + lrow;
            const u16* kp = kbase + (size_t)col * HIDN;
            bf16x8 kb0 = *(const bf16x8*)kp;
            bf16x8 kb1 = *(const bf16x8*)(kp + 32);
            c[cb] = mfma16(qa0, kb0, zf4());
            c[cb] = mfma16(qa1, kb1, c[cb]);
        }
        if (kt == dti) {
#pragma unroll
            for (int cb = 0; cb < 4; ++cb) {
                const int col = kt * 64 + cb * 16 + lrow;
                const float m8 = fmaf(am[col], LOG2E, NEG8_L2E);
#pragma unroll
                for (int reg = 0; reg < 4; ++reg) {
                    const int row = row0 + quad * 4 + reg;
                    const float p = (col <= row)
                        ? exp2f(fmaf(c[cb][reg], QS_L2E, m8)) * inv_l[reg] : 0.f;
                    pw[(quad * 4 + reg) * PSTR + cb * 16 + lrow] = p;
                }
            }
        } else {
#pragma unroll
            for (int cb = 0; cb < 4; ++cb) {
                const int col = kt * 64 + cb * 16 + lrow;
                const float m8 = fmaf(am[col], LOG2E, NEG8_L2E);
#pragma unroll
                for (int reg = 0; reg < 4; ++reg) {
                    const float p = exp2f(fmaf(c[cb][reg], QS_L2E, m8)) * inv_l[reg];
                    pw[(quad * 4 + reg) * PSTR + cb * 16 + lrow] = p;
                }
            }
        }
        // same-wave LDS write->read: compiler inserts lgkmcnt wait, no barrier

        // probs store: float4 lanes, 4 insts/tile, 256B contiguous segments
#pragma unroll
        for (int it = 0; it < 4; ++it) {
            const int r = it * 4 + quad;
            f32x4 v = *(const f32x4*)&pw[r * PSTR + lrow * 4];
            __builtin_nontemporal_store(
                v, (f32x4*)&probs[((size_t)bh * S_LEN + row0 + r) * S_LEN + kt * 64 + lrow * 4]);
        }

        // PV A-fragment from fp32 LDS, truncation-packed to bf16
        f32x4 p0 = *(const f32x4*)&pw[lrow * PSTR + quad * 8];
        f32x4 p1 = *(const f32x4*)&pw[lrow * PSTR + quad * 8 + 4];
        f32x4 p2 = *(const f32x4*)&pw[lrow * PSTR + 32 + quad * 8];
        f32x4 p3 = *(const f32x4*)&pw[lrow * PSTR + 32 + quad * 8 + 4];
        bf16x8 pa0 = pack8_trunc(p0, p1);
        bf16x8 pa1 = pack8_trunc(p2, p3);
#pragma unroll
        for (int db = 0; db < 4; ++db) {
            const u16* vp = vbase + (size_t)(db * 16 + lrow) * S_LEN + kt * 64;
            bf16x8 vb0 = *(const bf16x8*)vp;
            bf16x8 vb1 = *(const bf16x8*)(vp + 32);
            av[db] = mfma16(pa0, vb0, av[db]);
            av[db] = mfma16(pa1, vb1, av[db]);
        }
    }

    // ---- combine ctx partials across waves (overlaid on pfl) ----
    // Each wave only ever reads/writes its OWN pfl slice during pass 2, so
    // overwriting it here before the barrier is race-free. Swizzled slot
    // ((j + lane>>1) & 15) spreads lane*16 base across banks (2-way).
#pragma unroll
    for (int db = 0; db < 4; ++db)
#pragma unroll
        for (int reg = 0; reg < 4; ++reg)
            pw[lane * 16 + ((db * 4 + reg + (lane >> 1)) & 15)] = av[db][reg];
    __syncthreads();
    // wave wv owns output cols d = wv*16 + lrow
#pragma unroll
    for (int reg = 0; reg < 4; ++reg) {
        const int sl = lane * 16 + ((wv * 4 + reg + (lane >> 1)) & 15);
        const float s = pfl[0][sl] + pfl[1][sl] + pfl[2][sl] + pfl[3][sl];
        __builtin_nontemporal_store(
            s, &ctx[((size_t)b * S_LEN + row0 + quad * 4 + reg) * HIDN + h * HDIM + wv * 16 + lrow]);
    }
}

// ---------------------------------------------------------------------------
extern "C" void kernel_launch(void* const* d_in, const int* in_sizes, int n_in,
                              void* d_out, int out_size, void* d_ws, size_t ws_size,
                              hipStream_t stream)
{
    const float* hs    = (const float*)d_in[0];
    const float* amask = (const float*)d_in[1];
    const float* Wq    = (const float*)d_in[2];
    const float* bq    = (const float*)d_in[3];
    const float* Wk    = (const float*)d_in[4];
    const float* bk    = (const float*)d_in[5];
    const float* Wv    = (const float*)d_in[6];
    const float* bv    = (const float*)d_in[7];

    float* out   = (float*)d_out;
    float* ctx   = out;                                     // [2,2048,1024]
    float* probs = out + (size_t)NBATCH * S_LEN * HIDN;     // [2,16,2048,2048]

    const size_t NTOK = (size_t)NBATCH * S_LEN;             // 4096
    u16* hsb = (u16*)d_ws;                                  // bf16 [4096][1024]
    u16* Wqb = hsb + NTOK * HIDN;                           // bf16 [1024][1024]
    u16* Wkb = Wqb + (size_t)HIDN * HIDN;
    u16* Wvb = Wkb + (size_t)HIDN * HIDN;
    u16* Qf  = Wvb + (size_t)HIDN * HIDN;                   // bf16 [4096][1024]
    u16* Kf  = Qf + NTOK * HIDN;
    u16* Vt  = Kf + NTOK * HIDN;                            // bf16 [B][NH][64][2048]

    const int n_hs = (int)(NTOK * HIDN);
    const int n_w  = HIDN * HIDN;
    cvt_bf16<<<n_hs / 1024, 256, 0, stream>>>(hs, hsb, n_hs);
    cvt_bf16<<<n_w  / 1024, 256, 0, stream>>>(Wq, Wqb, n_w);
    cvt_bf16<<<n_w  / 1024, 256, 0, stream>>>(Wk, Wkb, n_w);
    cvt_bf16<<<n_w  / 1024, 256, 0, stream>>>(Wv, Wvb, n_w);

    qkv_gemm<<<dim3(32, 8, 3), 256, 0, stream>>>(hsb, Wqb, Wkb, Wvb, bq, bk, bv, Qf, Kf, Vt);
    attn_kernel<<<dim3(128, 16, 2), 256, 0, stream>>>(Qf, Kf, Vt, amask, ctx, probs);
}

// Round 3
// 768.794 us; speedup vs baseline: 1.2028x; 1.0131x over previous
//
#include <hip/hip_runtime.h>

#define S_LEN 2048
#define HIDN  1024
#define NHEAD 16
#define HDIM  64
#define NBATCH 2

typedef __bf16 bf16x8 __attribute__((ext_vector_type(8)));
typedef float  f32x4  __attribute__((ext_vector_type(4)));
typedef unsigned int  u32x4 __attribute__((ext_vector_type(4)));
typedef unsigned short u16;
typedef unsigned short u16x4 __attribute__((ext_vector_type(4)));

// exp(s*0.125 + m - 8) == exp2(s*QS_L2E + m*LOG2E - 8*LOG2E)
#define LOG2E      1.4426950408889634f
#define QS_L2E     0.18033688011112042f   /* 0.125 * log2(e) */
#define NEG8_L2E  -11.541560327111707f    /* -8 * log2(e)    */

#define PSTR 68   /* pfl leading-dim pad: 16B-aligned, 2-way banks on all 3 access patterns */

__device__ __forceinline__ u16 f2bf(float f) {
    union { float f; unsigned int u; } v; v.f = f;
    unsigned int u = v.u;
    unsigned int r = ((u >> 16) & 1u) + 0x7FFFu;
    return (u16)((u + r) >> 16);
}

__device__ __forceinline__ f32x4 mfma16(bf16x8 a, bf16x8 b, f32x4 c) {
    return __builtin_amdgcn_mfma_f32_16x16x32_bf16(a, b, c, 0, 0, 0);
}

__device__ __forceinline__ f32x4 zf4() { f32x4 z = {0.f, 0.f, 0.f, 0.f}; return z; }

// pack 8 fp32 -> 8 bf16 by truncation (v_perm grabs high halves, 1 inst / 2 elems)
__device__ __forceinline__ bf16x8 pack8_trunc(f32x4 a, f32x4 b) {
    union { f32x4 f; u32x4 u; } ua, ub;
    ua.f = a; ub.f = b;
    union { unsigned int d[4]; bf16x8 v; } r;
    r.d[0] = __builtin_amdgcn_perm(ua.u.y, ua.u.x, 0x07060302u);
    r.d[1] = __builtin_amdgcn_perm(ua.u.w, ua.u.z, 0x07060302u);
    r.d[2] = __builtin_amdgcn_perm(ub.u.y, ub.u.x, 0x07060302u);
    r.d[3] = __builtin_amdgcn_perm(ub.u.w, ub.u.z, 0x07060302u);
    return r.v;
}

// async global->LDS, 16B per lane; LDS dest must be wave-uniform base + lane*16
__device__ __forceinline__ void gld16(void* lds, const void* g) {
    __builtin_amdgcn_global_load_lds(
        (const __attribute__((address_space(1))) void*)g,
        (__attribute__((address_space(3))) void*)lds, 16, 0, 0);
}

// ---------------------------------------------------------------------------
// Kernel 0: fused fp32 -> bf16 convert, single launch for hs + Wq + Wk + Wv.
// ---------------------------------------------------------------------------
__global__ __launch_bounds__(256) void cvt_all(
    const float* __restrict__ hs, const float* __restrict__ Wq,
    const float* __restrict__ Wk, const float* __restrict__ Wv,
    u16* __restrict__ hsb, u16* __restrict__ Wqb,
    u16* __restrict__ Wkb, u16* __restrict__ Wvb)
{
    const int NBH = (NBATCH * S_LEN * HIDN) / 1024;   // 4096 blocks
    const int NBW = (HIDN * HIDN) / 1024;             // 1024 blocks each
    int bid = blockIdx.x;
    const float* __restrict__ s; u16* __restrict__ d;
    if (bid < NBH)                { s = hs; d = hsb; }
    else if (bid < NBH + NBW)     { s = Wq; d = Wqb; bid -= NBH; }
    else if (bid < NBH + 2 * NBW) { s = Wk; d = Wkb; bid -= NBH + NBW; }
    else                          { s = Wv; d = Wvb; bid -= NBH + 2 * NBW; }
    const int i = (bid * 256 + (int)threadIdx.x) * 4;
    float4 v = *(const float4*)&s[i];
    u16x4 o = { f2bf(v.x), f2bf(v.y), f2bf(v.z), f2bf(v.w) };
    *(u16x4*)&d[i] = o;
}

// ---------------------------------------------------------------------------
// Kernel 1: QKV projection, bf16 in/out.  out = hsb @ W^T + bias
// M=4096, N=1024, K=1024.  128x128 tile, BK=64 (was 32): 16 K-steps, half the
// barrier drains, 32 MFMA per phase.
// LDS 16B-chunk XOR swizzle (chunk ^= row&7) applied as inverse-permuted
// GLOBAL src (global_load_lds dest stays linear) + same XOR on ds_read ->
// conflict-free b128 reads at the 128B row stride (would be 2x otherwise).
// Operand roles swap per z:
//   z<2 : Rs=W rows (n), Cs=hsb rows (m)  -> C/D lane-local dim = n
//         -> Q/K epilogue uses u16x4 vector stores (16/thread, was 64 scalar).
//   z==2: Rs=hsb rows (m), Cs=W rows (n)  -> lane-local dim = token
//         -> Vt[b][h][d][s] u16x4 stores along s (as before).
// ---------------------------------------------------------------------------
__global__ __launch_bounds__(256) void qkv_gemm(
    const u16* __restrict__ hsb,
    const u16* __restrict__ Wqb, const u16* __restrict__ Wkb, const u16* __restrict__ Wvb,
    const float* __restrict__ bq, const float* __restrict__ bk, const float* __restrict__ bv,
    u16* __restrict__ Qf, u16* __restrict__ Kf, u16* __restrict__ Vt)
{
    __shared__ u16 Rs[128 * 64];   // row-operand tile (MFMA row dim = quad*4+reg)
    __shared__ u16 Cs[128 * 64];   // col-operand tile (MFMA col dim = lrow)

    const int z = blockIdx.z;
    const u16*   __restrict__ W    = (z == 0) ? Wqb : (z == 1) ? Wkb : Wvb;
    const float* __restrict__ bias = (z == 0) ? bq  : (z == 1) ? bk  : bv;

    const int mbase = blockIdx.x * 128;   // hsb (token) rows
    const int nbase = blockIdx.y * 128;   // W (output-feature) rows
    const u16* __restrict__ Rm = (z == 2) ? hsb : W;
    const u16* __restrict__ Cm = (z == 2) ? W   : hsb;
    const int rbase = (z == 2) ? mbase : nbase;
    const int cbase = (z == 2) ? nbase : mbase;

    const int tid  = threadIdx.x;
    const int lane = tid & 63;
    const int wv   = tid >> 6;
    const int wrow = wv >> 1, wcol = wv & 1;
    const int lrow = lane & 15, quad = lane >> 4;
    const int l7   = lrow & 7;

    // staging: 1024 16B-chunks per tile; thread t-th chunk = tid + t*256.
    // chunk c -> LDS linear c*16B; global src row = c>>3, 16B-col = (c&7)^(row&7)
    const u16* rp[4]; const u16* cp[4];
#pragma unroll
    for (int t = 0; t < 4; ++t) {
        const int c = tid + t * 256;
        const int r = c >> 3;
        const int o = ((c & 7) ^ (r & 7)) * 8;
        rp[t] = &Rm[(size_t)(rbase + r) * HIDN + o];
        cp[t] = &Cm[(size_t)(cbase + r) * HIDN + o];
    }

    f32x4 acc[4][4];
#pragma unroll
    for (int i = 0; i < 4; ++i)
#pragma unroll
        for (int j = 0; j < 4; ++j) acc[i][j] = zf4();

    for (int k0 = 0; k0 < HIDN; k0 += 64) {
#pragma unroll
        for (int t = 0; t < 4; ++t) {
            gld16(&Rs[(tid + t * 256) * 8], rp[t] + k0);
            gld16(&Cs[(tid + t * 256) * 8], cp[t] + k0);
        }
        __syncthreads();   // drains vmcnt -> staged tile visible
#pragma unroll
        for (int kk = 0; kk < 2; ++kk) {
            const int sc = ((kk * 4 + quad) ^ l7) * 8;   // swizzled 16B chunk
            bf16x8 af[4], bfr[4];
#pragma unroll
            for (int i = 0; i < 4; ++i)
                af[i] = *(const bf16x8*)&Rs[(wrow * 64 + i * 16 + lrow) * 64 + sc];
#pragma unroll
            for (int j = 0; j < 4; ++j)
                bfr[j] = *(const bf16x8*)&Cs[(wcol * 64 + j * 16 + lrow) * 64 + sc];
#pragma unroll
            for (int i = 0; i < 4; ++i)
#pragma unroll
                for (int j = 0; j < 4; ++j)
                    acc[i][j] = mfma16(af[i], bfr[j], acc[i][j]);
        }
        __syncthreads();   // protect LDS before next staging overwrite
    }

    // epilogue: C/D layout row(=R-operand dim) = quad*4+reg, col(=C-operand) = lrow
    if (z == 2) {
        // R = hsb -> lane-local dim = token; store u16x4 along s in Vt[b][h][d][s]
        const int bb = mbase >> 11;           // batch (uniform per block)
        const int sb = mbase & 2047;
#pragma unroll
        for (int i = 0; i < 4; ++i) {
#pragma unroll
            for (int j = 0; j < 4; ++j) {
                const int n = nbase + wcol * 64 + j * 16 + lrow;
                const int hh = n >> 6, d = n & 63;
                const float bs = bias[n];
                const int sbase = sb + wrow * 64 + i * 16 + quad * 4;
                u16x4 pk = { f2bf(acc[i][j][0] + bs), f2bf(acc[i][j][1] + bs),
                             f2bf(acc[i][j][2] + bs), f2bf(acc[i][j][3] + bs) };
                *(u16x4*)&Vt[(((size_t)(bb * NHEAD + hh)) * HDIM + d) * S_LEN + sbase] = pk;
            }
        }
    } else {
        // R = W -> lane-local dim = n; coalesced u16x4 stores into row-major Q/K
        u16* __restrict__ O = (z == 0) ? Qf : Kf;
#pragma unroll
        for (int i = 0; i < 4; ++i) {
#pragma unroll
            for (int j = 0; j < 4; ++j) {
                const int n0 = nbase + wrow * 64 + i * 16 + quad * 4;
                const int m  = mbase + wcol * 64 + j * 16 + lrow;
                const float4 b4 = *(const float4*)&bias[n0];
                u16x4 pk = { f2bf(acc[i][j][0] + b4.x), f2bf(acc[i][j][1] + b4.y),
                             f2bf(acc[i][j][2] + b4.z), f2bf(acc[i][j][3] + b4.w) };
                *(u16x4*)&O[(size_t)m * HIDN + n0] = pk;
            }
        }
    }
}

// ---------------------------------------------------------------------------
// Kernel 2: causal attention. Block = (b, h, 16-row q-tile), grid (128,16,2)
// = 4096 blocks. 4 waves split the kt (64-col) tiles. 17.7KB LDS -> 8
// blocks/CU, 100% wave occupancy; pfl stride 68 = <=2-way banks; ctx combine
// overlays pfl (own-wave overwrite pre-barrier is race-free).
// Round-0 vs round-2 A/B showed attn is insensitive to occupancy & conflicts
// -> throughput-bound (probs HBM writes + L2 K/V re-reads). Unchanged this
// round pending counter visibility.
// ---------------------------------------------------------------------------
__global__ __launch_bounds__(256) void attn_kernel(
    const u16* __restrict__ Qf,
    const u16* __restrict__ Kf,
    const u16* __restrict__ Vt,
    const float* __restrict__ amask,
    float* __restrict__ ctx,
    float* __restrict__ probs)
{
    const int qt = 127 - blockIdx.x;     // heavy blocks dispatch first
    const int h  = blockIdx.y;
    const int b  = blockIdx.z;
    const int bh = b * NHEAD + h;
    const int tid  = threadIdx.x;
    const int lane = tid & 63;
    const int wv   = tid >> 6;
    const int lrow = lane & 15, quad = lane >> 4;
    const int row0 = qt * 16;
    const int dti  = qt >> 2;            // diagonal tile index
    const int nkt  = dti + 1;            // # of 64-col tiles touching causal region

    __shared__ float pfl[4][16 * PSTR];  // wave-private fp32 P staging; combine overlay
    __shared__ float l_sh[4][16];

    // ---- zero-fill fully-masked probs tail (cols >= nkt*64) ----
    {
        const int tail  = nkt * 64;
        const int nt4   = (S_LEN - tail) >> 2;
        const int r  = tid >> 4;         // 16 threads per row
        const int c0 = tid & 15;
        const f32x4 zf = {0.f, 0.f, 0.f, 0.f};
        float* pr = &probs[((size_t)bh * S_LEN + row0 + r) * S_LEN + tail];
        for (int c4 = c0; c4 < nt4; c4 += 16)
            __builtin_nontemporal_store(zf, (f32x4*)&pr[c4 * 4]);
    }

    // ---- Q fragments ----
    const u16* qp = &Qf[((size_t)b * S_LEN + row0 + lrow) * HIDN + h * HDIM + quad * 8];
    const bf16x8 qa0 = *(const bf16x8*)qp;
    const bf16x8 qa1 = *(const bf16x8*)(qp + 32);

    const float* __restrict__ am = &amask[(size_t)b * S_LEN];
    const u16* __restrict__ kbase = &Kf[(size_t)b * S_LEN * HIDN + h * HDIM + quad * 8];

    // ---- pass 1: denominators ----
    float l_lane[4] = {0.f, 0.f, 0.f, 0.f};
    for (int kt = wv; kt < nkt; kt += 4) {
        f32x4 c[4];
#pragma unroll
        for (int cb = 0; cb < 4; ++cb) {
            const int col = kt * 64 + cb * 16 + lrow;
            const u16* kp = kbase + (size_t)col * HIDN;
            bf16x8 kb0 = *(const bf16x8*)kp;
            bf16x8 kb1 = *(const bf16x8*)(kp + 32);
            c[cb] = mfma16(qa0, kb0, zf4());
            c[cb] = mfma16(qa1, kb1, c[cb]);
        }
        if (kt == dti) {   // diagonal tile: causal compare
#pragma unroll
            for (int cb = 0; cb < 4; ++cb) {
                const int col = kt * 64 + cb * 16 + lrow;
                const float m8 = fmaf(am[col], LOG2E, NEG8_L2E);
#pragma unroll
                for (int reg = 0; reg < 4; ++reg) {
                    const int row = row0 + quad * 4 + reg;
                    const float e = exp2f(fmaf(c[cb][reg], QS_L2E, m8));
                    l_lane[reg] += (col <= row) ? e : 0.f;
                }
            }
        } else {           // interior: always unmasked
#pragma unroll
            for (int cb = 0; cb < 4; ++cb) {
                const int col = kt * 64 + cb * 16 + lrow;
                const float m8 = fmaf(am[col], LOG2E, NEG8_L2E);
#pragma unroll
                for (int reg = 0; reg < 4; ++reg)
                    l_lane[reg] += exp2f(fmaf(c[cb][reg], QS_L2E, m8));
            }
        }
    }
#pragma unroll
    for (int reg = 0; reg < 4; ++reg) {
#pragma unroll
        for (int off = 1; off < 16; off <<= 1)
            l_lane[reg] += __shfl_xor(l_lane[reg], off, 16);
    }
    if (lrow == 0) {
#pragma unroll
        for (int reg = 0; reg < 4; ++reg)
            l_sh[wv][quad * 4 + reg] = l_lane[reg];
    }
    __syncthreads();
    float inv_l[4];
#pragma unroll
    for (int reg = 0; reg < 4; ++reg) {
        const int rr = quad * 4 + reg;
        inv_l[reg] = 1.f / (l_sh[0][rr] + l_sh[1][rr] + l_sh[2][rr] + l_sh[3][rr]);
    }

    // ---- pass 2: probs + ctx partials ----
    f32x4 av[4];
#pragma unroll
    for (int db = 0; db < 4; ++db) av[db] = zf4();

    float* __restrict__ pw = pfl[wv];
    const u16* __restrict__ vbase = &Vt[(size_t)bh * HDIM * S_LEN + quad * 8];

    for (int kt = wv; kt < nkt; kt += 4) {
        f32x4 c[4];
#pragma unroll
        for (int cb = 0; cb < 4; ++cb) {
            const int col = kt * 64 + cb * 16 + lrow;
            const u16* kp = kbase + (size_t)col * HIDN;
            bf16x8 kb0 = *(const bf16x8*)kp;
            bf16x8 kb1 = *(const bf16x8*)(kp + 32);
            c[cb] = mfma16(qa0, kb0, zf4());
            c[cb] = mfma16(qa1, kb1, c[cb]);
        }
        if (kt == dti) {
#pragma unroll
            for (int cb = 0; cb < 4; ++cb) {
                const int col = kt * 64 + cb * 16 + lrow;
                const float m8 = fmaf(am[col], LOG2E, NEG8_L2E);
#pragma unroll
                for (int reg = 0; reg < 4; ++reg) {
                    const int row = row0 + quad * 4 + reg;
                    const float p = (col <= row)
                        ? exp2f(fmaf(c[cb][reg], QS_L2E, m8)) * inv_l[reg] : 0.f;
                    pw[(quad * 4 + reg) * PSTR + cb * 16 + lrow] = p;
                }
            }
        } else {
#pragma unroll
            for (int cb = 0; cb < 4; ++cb) {
                const int col = kt * 64 + cb * 16 + lrow;
                const float m8 = fmaf(am[col], LOG2E, NEG8_L2E);
#pragma unroll
                for (int reg = 0; reg < 4; ++reg) {
                    const float p = exp2f(fmaf(c[cb][reg], QS_L2E, m8)) * inv_l[reg];
                    pw[(quad * 4 + reg) * PSTR + cb * 16 + lrow] = p;
                }
            }
        }
        // same-wave LDS write->read: compiler inserts lgkmcnt wait, no barrier

        // probs store: float4 lanes, 4 insts/tile, 256B contiguous segments
#pragma unroll
        for (int it = 0; it < 4; ++it) {
            const int r = it * 4 + quad;
            f32x4 v = *(const f32x4*)&pw[r * PSTR + lrow * 4];
            __builtin_nontemporal_store(
                v, (f32x4*)&probs[((size_t)bh * S_LEN + row0 + r) * S_LEN + kt * 64 + lrow * 4]);
        }

        // PV A-fragment from fp32 LDS, truncation-packed to bf16
        f32x4 p0 = *(const f32x4*)&pw[lrow * PSTR + quad * 8];
        f32x4 p1 = *(const f32x4*)&pw[lrow * PSTR + quad * 8 + 4];
        f32x4 p2 = *(const f32x4*)&pw[lrow * PSTR + 32 + quad * 8];
        f32x4 p3 = *(const f32x4*)&pw[lrow * PSTR + 32 + quad * 8 + 4];
        bf16x8 pa0 = pack8_trunc(p0, p1);
        bf16x8 pa1 = pack8_trunc(p2, p3);
#pragma unroll
        for (int db = 0; db < 4; ++db) {
            const u16* vp = vbase + (size_t)(db * 16 + lrow) * S_LEN + kt * 64;
            bf16x8 vb0 = *(const bf16x8*)vp;
            bf16x8 vb1 = *(const bf16x8*)(vp + 32);
            av[db] = mfma16(pa0, vb0, av[db]);
            av[db] = mfma16(pa1, vb1, av[db]);
        }
    }

    // ---- combine ctx partials across waves (overlaid on pfl) ----
#pragma unroll
    for (int db = 0; db < 4; ++db)
#pragma unroll
        for (int reg = 0; reg < 4; ++reg)
            pw[lane * 16 + ((db * 4 + reg + (lane >> 1)) & 15)] = av[db][reg];
    __syncthreads();
    // wave wv owns output cols d = wv*16 + lrow
#pragma unroll
    for (int reg = 0; reg < 4; ++reg) {
        const int sl = lane * 16 + ((wv * 4 + reg + (lane >> 1)) & 15);
        const float s = pfl[0][sl] + pfl[1][sl] + pfl[2][sl] + pfl[3][sl];
        __builtin_nontemporal_store(
            s, &ctx[((size_t)b * S_LEN + row0 + quad * 4 + reg) * HIDN + h * HDIM + wv * 16 + lrow]);
    }
}

// ---------------------------------------------------------------------------
extern "C" void kernel_launch(void* const* d_in, const int* in_sizes, int n_in,
                              void* d_out, int out_size, void* d_ws, size_t ws_size,
                              hipStream_t stream)
{
    const float* hs    = (const float*)d_in[0];
    const float* amask = (const float*)d_in[1];
    const float* Wq    = (const float*)d_in[2];
    const float* bq    = (const float*)d_in[3];
    const float* Wk    = (const float*)d_in[4];
    const float* bk    = (const float*)d_in[5];
    const float* Wv    = (const float*)d_in[6];
    const float* bv    = (const float*)d_in[7];

    float* out   = (float*)d_out;
    float* ctx   = out;                                     // [2,2048,1024]
    float* probs = out + (size_t)NBATCH * S_LEN * HIDN;     // [2,16,2048,2048]

    const size_t NTOK = (size_t)NBATCH * S_LEN;             // 4096
    u16* hsb = (u16*)d_ws;                                  // bf16 [4096][1024]
    u16* Wqb = hsb + NTOK * HIDN;                           // bf16 [1024][1024]
    u16* Wkb = Wqb + (size_t)HIDN * HIDN;
    u16* Wvb = Wkb + (size_t)HIDN * HIDN;
    u16* Qf  = Wvb + (size_t)HIDN * HIDN;                   // bf16 [4096][1024]
    u16* Kf  = Qf + NTOK * HIDN;
    u16* Vt  = Kf + NTOK * HIDN;                            // bf16 [B][NH][64][2048]

    const int nblk_cvt = (int)(NTOK * HIDN / 1024) + 3 * (HIDN * HIDN / 1024);  // 7168
    cvt_all<<<nblk_cvt, 256, 0, stream>>>(hs, Wq, Wk, Wv, hsb, Wqb, Wkb, Wvb);

    qkv_gemm<<<dim3(32, 8, 3), 256, 0, stream>>>(hsb, Wqb, Wkb, Wvb, bq, bk, bv, Qf, Kf, Vt);
    attn_kernel<<<dim3(128, 16, 2), 256, 0, stream>>>(Qf, Kf, Vt, amask, ctx, probs);
}

// Round 5
// 762.103 us; speedup vs baseline: 1.2134x; 1.0088x over previous
//
#include <hip/hip_runtime.h>

#define S_LEN 2048
#define HIDN  1024
#define NHEAD 16
#define HDIM  64
#define NBATCH 2

typedef __bf16 bf16x8 __attribute__((ext_vector_type(8)));
typedef float  f32x4  __attribute__((ext_vector_type(4)));
typedef unsigned int  u32x4 __attribute__((ext_vector_type(4)));
typedef unsigned short u16;
typedef unsigned short u16x4 __attribute__((ext_vector_type(4)));

// exp(s*0.125 + m - 8) == exp2(s*QS_L2E + m*LOG2E - 8*LOG2E)
#define LOG2E      1.4426950408889634f
#define QS_L2E     0.18033688011112042f   /* 0.125 * log2(e) */
#define NEG8_L2E  -11.541560327111707f    /* -8 * log2(e)    */

#define PSTR 68   /* pfl leading-dim pad: 16B-aligned, 2-way banks on all 3 access patterns */

__device__ __forceinline__ u16 f2bf(float f) {
    union { float f; unsigned int u; } v; v.f = f;
    unsigned int u = v.u;
    unsigned int r = ((u >> 16) & 1u) + 0x7FFFu;
    return (u16)((u + r) >> 16);
}

__device__ __forceinline__ f32x4 mfma16(bf16x8 a, bf16x8 b, f32x4 c) {
    return __builtin_amdgcn_mfma_f32_16x16x32_bf16(a, b, c, 0, 0, 0);
}

__device__ __forceinline__ f32x4 zf4() { f32x4 z = {0.f, 0.f, 0.f, 0.f}; return z; }

// pack 8 fp32 -> 8 bf16 by truncation (v_perm grabs high halves, 1 inst / 2 elems)
__device__ __forceinline__ bf16x8 pack8_trunc(f32x4 a, f32x4 b) {
    union { f32x4 f; u32x4 u; } ua, ub;
    ua.f = a; ub.f = b;
    union { unsigned int d[4]; bf16x8 v; } r;
    r.d[0] = __builtin_amdgcn_perm(ua.u.y, ua.u.x, 0x07060302u);
    r.d[1] = __builtin_amdgcn_perm(ua.u.w, ua.u.z, 0x07060302u);
    r.d[2] = __builtin_amdgcn_perm(ub.u.y, ub.u.x, 0x07060302u);
    r.d[3] = __builtin_amdgcn_perm(ub.u.w, ub.u.z, 0x07060302u);
    return r.v;
}

// async global->LDS, 16B per lane; LDS dest must be wave-uniform base + lane*16
__device__ __forceinline__ void gld16(void* lds, const void* g) {
    __builtin_amdgcn_global_load_lds(
        (const __attribute__((address_space(1))) void*)g,
        (__attribute__((address_space(3))) void*)lds, 16, 0, 0);
}

// ---------------------------------------------------------------------------
// Kernel 0: fused fp32 -> bf16 convert, single launch for hs + Wq + Wk + Wv.
// ---------------------------------------------------------------------------
__global__ __launch_bounds__(256) void cvt_all(
    const float* __restrict__ hs, const float* __restrict__ Wq,
    const float* __restrict__ Wk, const float* __restrict__ Wv,
    u16* __restrict__ hsb, u16* __restrict__ Wqb,
    u16* __restrict__ Wkb, u16* __restrict__ Wvb)
{
    const int NBH = (NBATCH * S_LEN * HIDN) / 1024;   // 4096 blocks
    const int NBW = (HIDN * HIDN) / 1024;             // 1024 blocks each
    int bid = blockIdx.x;
    const float* __restrict__ s; u16* __restrict__ d;
    if (bid < NBH)                { s = hs; d = hsb; }
    else if (bid < NBH + NBW)     { s = Wq; d = Wqb; bid -= NBH; }
    else if (bid < NBH + 2 * NBW) { s = Wk; d = Wkb; bid -= NBH + NBW; }
    else                          { s = Wv; d = Wvb; bid -= NBH + 2 * NBW; }
    const int i = (bid * 256 + (int)threadIdx.x) * 4;
    float4 v = *(const float4*)&s[i];
    u16x4 o = { f2bf(v.x), f2bf(v.y), f2bf(v.z), f2bf(v.w) };
    *(u16x4*)&d[i] = o;
}

// ---------------------------------------------------------------------------
// Kernel 1: FUSED QKV projection. One block computes the Q, K and V outputs
// for a 128-token x 64-feature tile, so the hsb A-tile is staged ONCE per
// K-step and feeds all three W operands: 10 global_load_lds -> 48 MFMA per
// K-step per wave (was 8 -> 32 across 3 separate kernels). Barriers per
// useful FLOP drop 2.4x; hsb traffic drops 3x.
// Fragment trick: 16x16x32 MFMA A- and B-fragment lane layouts are identical,
// so the hs fragments serve as B-operand for Q/K (n lane-local -> coalesced
// u16x4 epilogue into row-major Qf/Kf) and as A-operand for V (token
// lane-local -> u16x4 along s into Vt[b][h][d][s]).
// BK=64, 16B-chunk XOR swizzle: global src pre-swizzled (linear gld dest),
// same XOR on ds_read -> conflict-free b128 at 128B row stride.
// LDS 40KB, grid (32,16) = 512 blocks = 2/CU, ~96 acc VGPR.
// ---------------------------------------------------------------------------
__global__ __launch_bounds__(256) void qkv_fused(
    const u16* __restrict__ hsb,
    const u16* __restrict__ Wqb, const u16* __restrict__ Wkb, const u16* __restrict__ Wvb,
    const float* __restrict__ bq, const float* __restrict__ bk, const float* __restrict__ bv,
    u16* __restrict__ Qf, u16* __restrict__ Kf, u16* __restrict__ Vt)
{
    __shared__ u16 As[128 * 64];        // hsb tile: 128 tokens x 64 K
    __shared__ u16 Bs[3][64 * 64];      // W tiles: 64 n-rows x 64 K each

    const int mbase = blockIdx.x * 128;   // token rows
    const int nbase = blockIdx.y * 64;    // output-feature rows
    const int tid  = threadIdx.x;
    const int lane = tid & 63;
    const int wv   = tid >> 6;
    const int wm   = wv >> 1, wn = wv & 1;   // wave grid: 2 (m) x 2 (n)
    const int lrow = lane & 15, quad = lane >> 4;
    const int l7   = lrow & 7;

    const u16* __restrict__ Wm[3] = { Wqb, Wkb, Wvb };

    // staging pointers. A: 1024 chunks (4/thread); each B: 512 chunks (2/thread).
    // chunk c -> LDS linear c*16B; global src row = c>>3, 16B-col = (c&7)^(row&7)
    const u16* ap[4];
#pragma unroll
    for (int t = 0; t < 4; ++t) {
        const int c = tid + t * 256;
        const int r = c >> 3;
        const int o = ((c & 7) ^ (r & 7)) * 8;
        ap[t] = &hsb[(size_t)(mbase + r) * HIDN + o];
    }
    const u16* bp[3][2];
#pragma unroll
    for (int z = 0; z < 3; ++z)
#pragma unroll
        for (int t = 0; t < 2; ++t) {
            const int c = tid + t * 256;
            const int r = c >> 3;
            const int o = ((c & 7) ^ (r & 7)) * 8;
            bp[z][t] = &Wm[z][(size_t)(nbase + r) * HIDN + o];
        }

    f32x4 accqk[2][2][4];   // [z][j][i]: C-row = n (quad*4+reg), C-col = token (lrow)
    f32x4 accv[4][2];       // [i][j]:    C-row = token,          C-col = n
#pragma unroll
    for (int z = 0; z < 2; ++z)
#pragma unroll
        for (int j = 0; j < 2; ++j)
#pragma unroll
            for (int i = 0; i < 4; ++i) accqk[z][j][i] = zf4();
#pragma unroll
    for (int i = 0; i < 4; ++i)
#pragma unroll
        for (int j = 0; j < 2; ++j) accv[i][j] = zf4();

    for (int k0 = 0; k0 < HIDN; k0 += 64) {
#pragma unroll
        for (int t = 0; t < 4; ++t)
            gld16(&As[(tid + t * 256) * 8], ap[t] + k0);
#pragma unroll
        for (int z = 0; z < 3; ++z)
#pragma unroll
            for (int t = 0; t < 2; ++t)
                gld16(&Bs[z][(tid + t * 256) * 8], bp[z][t] + k0);
        __syncthreads();   // drains vmcnt -> staged tiles visible

#pragma unroll
        for (int kk = 0; kk < 2; ++kk) {
            const int sc = ((kk * 4 + quad) ^ l7) * 8;   // swizzled 16B chunk
            bf16x8 hf[4], wf[3][2];
#pragma unroll
            for (int i = 0; i < 4; ++i)
                hf[i] = *(const bf16x8*)&As[(wm * 64 + i * 16 + lrow) * 64 + sc];
#pragma unroll
            for (int z = 0; z < 3; ++z)
#pragma unroll
                for (int j = 0; j < 2; ++j)
                    wf[z][j] = *(const bf16x8*)&Bs[z][(wn * 32 + j * 16 + lrow) * 64 + sc];
            // Q,K: af = W (n lane-local), bf = hs
#pragma unroll
            for (int z = 0; z < 2; ++z)
#pragma unroll
                for (int j = 0; j < 2; ++j)
#pragma unroll
                    for (int i = 0; i < 4; ++i)
                        accqk[z][j][i] = mfma16(wf[z][j], hf[i], accqk[z][j][i]);
            // V: af = hs (token lane-local), bf = W
#pragma unroll
            for (int i = 0; i < 4; ++i)
#pragma unroll
                for (int j = 0; j < 2; ++j)
                    accv[i][j] = mfma16(hf[i], wf[2][j], accv[i][j]);
        }
        __syncthreads();   // protect LDS before next staging overwrite
    }

    // ---- Q/K epilogue: n lane-local -> u16x4 along n into row-major Qf/Kf ----
#pragma unroll
    for (int z = 0; z < 2; ++z) {
        u16* __restrict__ O = (z == 0) ? Qf : Kf;
        const float* __restrict__ bias = (z == 0) ? bq : bk;
#pragma unroll
        for (int j = 0; j < 2; ++j) {
#pragma unroll
            for (int i = 0; i < 4; ++i) {
                const int n0 = nbase + wn * 32 + j * 16 + quad * 4;
                const int m  = mbase + wm * 64 + i * 16 + lrow;
                const float4 b4 = *(const float4*)&bias[n0];
                u16x4 pk = { f2bf(accqk[z][j][i][0] + b4.x), f2bf(accqk[z][j][i][1] + b4.y),
                             f2bf(accqk[z][j][i][2] + b4.z), f2bf(accqk[z][j][i][3] + b4.w) };
                *(u16x4*)&O[(size_t)m * HIDN + n0] = pk;
            }
        }
    }
    // ---- V epilogue: token lane-local -> u16x4 along s into Vt[b][h][d][s] ----
    {
        const int bb = mbase >> 11;           // batch (uniform per block)
        const int sb = mbase & 2047;
#pragma unroll
        for (int i = 0; i < 4; ++i) {
#pragma unroll
            for (int j = 0; j < 2; ++j) {
                const int n = nbase + wn * 32 + j * 16 + lrow;
                const int hh = n >> 6, d = n & 63;
                const float bs = bv[n];
                const int s0 = sb + wm * 64 + i * 16 + quad * 4;
                u16x4 pk = { f2bf(accv[i][j][0] + bs), f2bf(accv[i][j][1] + bs),
                             f2bf(accv[i][j][2] + bs), f2bf(accv[i][j][3] + bs) };
                *(u16x4*)&Vt[(((size_t)(bb * NHEAD + hh)) * HDIM + d) * S_LEN + s0] = pk;
            }
        }
    }
}

// ---------------------------------------------------------------------------
// Kernel 2: causal attention. Block = (b, h, 16-row q-tile), grid (128,16,2)
// = 4096 blocks. 4 waves split the kt (64-col) tiles. 17.7KB LDS -> 8
// blocks/CU, 100% wave occupancy; pfl stride 68 = <=2-way banks; ctx combine
// overlays pfl (own-wave overwrite pre-barrier is race-free).
// Round-0 vs round-2 A/B showed attn is insensitive to occupancy & conflicts
// -> throughput-bound (probs HBM writes + L2 K/V re-reads). Unchanged this
// round; if round-5 delta is ~0, attn is ~345us and becomes the sole target.
// ---------------------------------------------------------------------------
__global__ __launch_bounds__(256) void attn_kernel(
    const u16* __restrict__ Qf,
    const u16* __restrict__ Kf,
    const u16* __restrict__ Vt,
    const float* __restrict__ amask,
    float* __restrict__ ctx,
    float* __restrict__ probs)
{
    const int qt = 127 - blockIdx.x;     // heavy blocks dispatch first
    const int h  = blockIdx.y;
    const int b  = blockIdx.z;
    const int bh = b * NHEAD + h;
    const int tid  = threadIdx.x;
    const int lane = tid & 63;
    const int wv   = tid >> 6;
    const int lrow = lane & 15, quad = lane >> 4;
    const int row0 = qt * 16;
    const int dti  = qt >> 2;            // diagonal tile index
    const int nkt  = dti + 1;            // # of 64-col tiles touching causal region

    __shared__ float pfl[4][16 * PSTR];  // wave-private fp32 P staging; combine overlay
    __shared__ float l_sh[4][16];

    // ---- zero-fill fully-masked probs tail (cols >= nkt*64) ----
    {
        const int tail  = nkt * 64;
        const int nt4   = (S_LEN - tail) >> 2;
        const int r  = tid >> 4;         // 16 threads per row
        const int c0 = tid & 15;
        const f32x4 zf = {0.f, 0.f, 0.f, 0.f};
        float* pr = &probs[((size_t)bh * S_LEN + row0 + r) * S_LEN + tail];
        for (int c4 = c0; c4 < nt4; c4 += 16)
            __builtin_nontemporal_store(zf, (f32x4*)&pr[c4 * 4]);
    }

    // ---- Q fragments ----
    const u16* qp = &Qf[((size_t)b * S_LEN + row0 + lrow) * HIDN + h * HDIM + quad * 8];
    const bf16x8 qa0 = *(const bf16x8*)qp;
    const bf16x8 qa1 = *(const bf16x8*)(qp + 32);

    const float* __restrict__ am = &amask[(size_t)b * S_LEN];
    const u16* __restrict__ kbase = &Kf[(size_t)b * S_LEN * HIDN + h * HDIM + quad * 8];

    // ---- pass 1: denominators ----
    float l_lane[4] = {0.f, 0.f, 0.f, 0.f};
    for (int kt = wv; kt < nkt; kt += 4) {
        f32x4 c[4];
#pragma unroll
        for (int cb = 0; cb < 4; ++cb) {
            const int col = kt * 64 + cb * 16 + lrow;
            const u16* kp = kbase + (size_t)col * HIDN;
            bf16x8 kb0 = *(const bf16x8*)kp;
            bf16x8 kb1 = *(const bf16x8*)(kp + 32);
            c[cb] = mfma16(qa0, kb0, zf4());
            c[cb] = mfma16(qa1, kb1, c[cb]);
        }
        if (kt == dti) {   // diagonal tile: causal compare
#pragma unroll
            for (int cb = 0; cb < 4; ++cb) {
                const int col = kt * 64 + cb * 16 + lrow;
                const float m8 = fmaf(am[col], LOG2E, NEG8_L2E);
#pragma unroll
                for (int reg = 0; reg < 4; ++reg) {
                    const int row = row0 + quad * 4 + reg;
                    const float e = exp2f(fmaf(c[cb][reg], QS_L2E, m8));
                    l_lane[reg] += (col <= row) ? e : 0.f;
                }
            }
        } else {           // interior: always unmasked
#pragma unroll
            for (int cb = 0; cb < 4; ++cb) {
                const int col = kt * 64 + cb * 16 + lrow;
                const float m8 = fmaf(am[col], LOG2E, NEG8_L2E);
#pragma unroll
                for (int reg = 0; reg < 4; ++reg)
                    l_lane[reg] += exp2f(fmaf(c[cb][reg], QS_L2E, m8));
            }
        }
    }
#pragma unroll
    for (int reg = 0; reg < 4; ++reg) {
#pragma unroll
        for (int off = 1; off < 16; off <<= 1)
            l_lane[reg] += __shfl_xor(l_lane[reg], off, 16);
    }
    if (lrow == 0) {
#pragma unroll
        for (int reg = 0; reg < 4; ++reg)
            l_sh[wv][quad * 4 + reg] = l_lane[reg];
    }
    __syncthreads();
    float inv_l[4];
#pragma unroll
    for (int reg = 0; reg < 4; ++reg) {
        const int rr = quad * 4 + reg;
        inv_l[reg] = 1.f / (l_sh[0][rr] + l_sh[1][rr] + l_sh[2][rr] + l_sh[3][rr]);
    }

    // ---- pass 2: probs + ctx partials ----
    f32x4 av[4];
#pragma unroll
    for (int db = 0; db < 4; ++db) av[db] = zf4();

    float* __restrict__ pw = pfl[wv];
    const u16* __restrict__ vbase = &Vt[(size_t)bh * HDIM * S_LEN + quad * 8];

    for (int kt = wv; kt < nkt; kt += 4) {
        f32x4 c[4];
#pragma unroll
        for (int cb = 0; cb < 4; ++cb) {
            const int col = kt * 64 + cb * 16 + lrow;
            const u16* kp = kbase + (size_t)col * HIDN;
            bf16x8 kb0 = *(const bf16x8*)kp;
            bf16x8 kb1 = *(const bf16x8*)(kp + 32);
            c[cb] = mfma16(qa0, kb0, zf4());
            c[cb] = mfma16(qa1, kb1, c[cb]);
        }
        if (kt == dti) {
#pragma unroll
            for (int cb = 0; cb < 4; ++cb) {
                const int col = kt * 64 + cb * 16 + lrow;
                const float m8 = fmaf(am[col], LOG2E, NEG8_L2E);
#pragma unroll
                for (int reg = 0; reg < 4; ++reg) {
                    const int row = row0 + quad * 4 + reg;
                    const float p = (col <= row)
                        ? exp2f(fmaf(c[cb][reg], QS_L2E, m8)) * inv_l[reg] : 0.f;
                    pw[(quad * 4 + reg) * PSTR + cb * 16 + lrow] = p;
                }
            }
        } else {
#pragma unroll
            for (int cb = 0; cb < 4; ++cb) {
                const int col = kt * 64 + cb * 16 + lrow;
                const float m8 = fmaf(am[col], LOG2E, NEG8_L2E);
#pragma unroll
                for (int reg = 0; reg < 4; ++reg) {
                    const float p = exp2f(fmaf(c[cb][reg], QS_L2E, m8)) * inv_l[reg];
                    pw[(quad * 4 + reg) * PSTR + cb * 16 + lrow] = p;
                }
            }
        }
        // same-wave LDS write->read: compiler inserts lgkmcnt wait, no barrier

        // probs store: float4 lanes, 4 insts/tile, 256B contiguous segments
#pragma unroll
        for (int it = 0; it < 4; ++it) {
            const int r = it * 4 + quad;
            f32x4 v = *(const f32x4*)&pw[r * PSTR + lrow * 4];
            __builtin_nontemporal_store(
                v, (f32x4*)&probs[((size_t)bh * S_LEN + row0 + r) * S_LEN + kt * 64 + lrow * 4]);
        }

        // PV A-fragment from fp32 LDS, truncation-packed to bf16
        f32x4 p0 = *(const f32x4*)&pw[lrow * PSTR + quad * 8];
        f32x4 p1 = *(const f32x4*)&pw[lrow * PSTR + quad * 8 + 4];
        f32x4 p2 = *(const f32x4*)&pw[lrow * PSTR + 32 + quad * 8];
        f32x4 p3 = *(const f32x4*)&pw[lrow * PSTR + 32 + quad * 8 + 4];
        bf16x8 pa0 = pack8_trunc(p0, p1);
        bf16x8 pa1 = pack8_trunc(p2, p3);
#pragma unroll
        for (int db = 0; db < 4; ++db) {
            const u16* vp = vbase + (size_t)(db * 16 + lrow) * S_LEN + kt * 64;
            bf16x8 vb0 = *(const bf16x8*)vp;
            bf16x8 vb1 = *(const bf16x8*)(vp + 32);
            av[db] = mfma16(pa0, vb0, av[db]);
            av[db] = mfma16(pa1, vb1, av[db]);
        }
    }

    // ---- combine ctx partials across waves (overlaid on pfl) ----
#pragma unroll
    for (int db = 0; db < 4; ++db)
#pragma unroll
        for (int reg = 0; reg < 4; ++reg)
            pw[lane * 16 + ((db * 4 + reg + (lane >> 1)) & 15)] = av[db][reg];
    __syncthreads();
    // wave wv owns output cols d = wv*16 + lrow
#pragma unroll
    for (int reg = 0; reg < 4; ++reg) {
        const int sl = lane * 16 + ((wv * 4 + reg + (lane >> 1)) & 15);
        const float s = pfl[0][sl] + pfl[1][sl] + pfl[2][sl] + pfl[3][sl];
        __builtin_nontemporal_store(
            s, &ctx[((size_t)b * S_LEN + row0 + quad * 4 + reg) * HIDN + h * HDIM + wv * 16 + lrow]);
    }
}

// ---------------------------------------------------------------------------
extern "C" void kernel_launch(void* const* d_in, const int* in_sizes, int n_in,
                              void* d_out, int out_size, void* d_ws, size_t ws_size,
                              hipStream_t stream)
{
    const float* hs    = (const float*)d_in[0];
    const float* amask = (const float*)d_in[1];
    const float* Wq    = (const float*)d_in[2];
    const float* bq    = (const float*)d_in[3];
    const float* Wk    = (const float*)d_in[4];
    const float* bk    = (const float*)d_in[5];
    const float* Wv    = (const float*)d_in[6];
    const float* bv    = (const float*)d_in[7];

    float* out   = (float*)d_out;
    float* ctx   = out;                                     // [2,2048,1024]
    float* probs = out + (size_t)NBATCH * S_LEN * HIDN;     // [2,16,2048,2048]

    const size_t NTOK = (size_t)NBATCH * S_LEN;             // 4096
    u16* hsb = (u16*)d_ws;                                  // bf16 [4096][1024]
    u16* Wqb = hsb + NTOK * HIDN;                           // bf16 [1024][1024]
    u16* Wkb = Wqb + (size_t)HIDN * HIDN;
    u16* Wvb = Wkb + (size_t)HIDN * HIDN;
    u16* Qf  = Wvb + (size_t)HIDN * HIDN;                   // bf16 [4096][1024]
    u16* Kf  = Qf + NTOK * HIDN;
    u16* Vt  = Kf + NTOK * HIDN;                            // bf16 [B][NH][64][2048]

    const int nblk_cvt = (int)(NTOK * HIDN / 1024) + 3 * (HIDN * HIDN / 1024);  // 7168
    cvt_all<<<nblk_cvt, 256, 0, stream>>>(hs, Wq, Wk, Wv, hsb, Wqb, Wkb, Wvb);

    qkv_fused<<<dim3(32, 16), 256, 0, stream>>>(hsb, Wqb, Wkb, Wvb, bq, bk, bv, Qf, Kf, Vt);
    attn_kernel<<<dim3(128, 16, 2), 256, 0, stream>>>(Qf, Kf, Vt, amask, ctx, probs);
}

// Round 6
// 701.221 us; speedup vs baseline: 1.3187x; 1.0868x over previous
//
#include <hip/hip_runtime.h>

#define S_LEN 2048
#define HIDN  1024
#define NHEAD 16
#define HDIM  64
#define NBATCH 2

typedef __bf16 bf16x8 __attribute__((ext_vector_type(8)));
typedef float  f32x4  __attribute__((ext_vector_type(4)));
typedef unsigned int  u32x4 __attribute__((ext_vector_type(4)));
typedef unsigned short u16;
typedef unsigned short u16x4 __attribute__((ext_vector_type(4)));

// exp(s*0.125 + m - 8) == exp2(s*QS_L2E + m*LOG2E - 8*LOG2E)
#define LOG2E      1.4426950408889634f
#define QS_L2E     0.18033688011112042f   /* 0.125 * log2(e) */
#define NEG8_L2E  -11.541560327111707f    /* -8 * log2(e)    */

__device__ __forceinline__ u16 f2bf(float f) {
    union { float f; unsigned int u; } v; v.f = f;
    unsigned int u = v.u;
    unsigned int r = ((u >> 16) & 1u) + 0x7FFFu;
    return (u16)((u + r) >> 16);
}

__device__ __forceinline__ float bf2f(u16 h) {
    union { unsigned int u; float f; } v; v.u = ((unsigned int)h) << 16;
    return v.f;
}

__device__ __forceinline__ f32x4 mfma16(bf16x8 a, bf16x8 b, f32x4 c) {
    return __builtin_amdgcn_mfma_f32_16x16x32_bf16(a, b, c, 0, 0, 0);
}

__device__ __forceinline__ f32x4 zf4() { f32x4 z = {0.f, 0.f, 0.f, 0.f}; return z; }

// async global->LDS, 16B per lane; LDS dest must be wave-uniform base + lane*16
__device__ __forceinline__ void gld16(void* lds, const void* g) {
    __builtin_amdgcn_global_load_lds(
        (const __attribute__((address_space(1))) void*)g,
        (__attribute__((address_space(3))) void*)lds, 16, 0, 0);
}

// ---------------------------------------------------------------------------
// Kernel 0: fused fp32 -> bf16 convert, single launch for hs + Wq + Wk + Wv.
// ---------------------------------------------------------------------------
__global__ __launch_bounds__(256) void cvt_all(
    const float* __restrict__ hs, const float* __restrict__ Wq,
    const float* __restrict__ Wk, const float* __restrict__ Wv,
    u16* __restrict__ hsb, u16* __restrict__ Wqb,
    u16* __restrict__ Wkb, u16* __restrict__ Wvb)
{
    const int NBH = (NBATCH * S_LEN * HIDN) / 1024;   // 4096 blocks
    const int NBW = (HIDN * HIDN) / 1024;             // 1024 blocks each
    int bid = blockIdx.x;
    const float* __restrict__ s; u16* __restrict__ d;
    if (bid < NBH)                { s = hs; d = hsb; }
    else if (bid < NBH + NBW)     { s = Wq; d = Wqb; bid -= NBH; }
    else if (bid < NBH + 2 * NBW) { s = Wk; d = Wkb; bid -= NBH + NBW; }
    else                          { s = Wv; d = Wvb; bid -= NBH + 2 * NBW; }
    const int i = (bid * 256 + (int)threadIdx.x) * 4;
    float4 v = *(const float4*)&s[i];
    u16x4 o = { f2bf(v.x), f2bf(v.y), f2bf(v.z), f2bf(v.w) };
    *(u16x4*)&d[i] = o;
}

// ---------------------------------------------------------------------------
// Kernel 1: FUSED QKV projection (unchanged from round 5; measured ~neutral
// vs 3-kernel, kept for the single launch + 3x less hsb traffic).
// ---------------------------------------------------------------------------
__global__ __launch_bounds__(256) void qkv_fused(
    const u16* __restrict__ hsb,
    const u16* __restrict__ Wqb, const u16* __restrict__ Wkb, const u16* __restrict__ Wvb,
    const float* __restrict__ bq, const float* __restrict__ bk, const float* __restrict__ bv,
    u16* __restrict__ Qf, u16* __restrict__ Kf, u16* __restrict__ Vt)
{
    __shared__ u16 As[128 * 64];        // hsb tile: 128 tokens x 64 K
    __shared__ u16 Bs[3][64 * 64];      // W tiles: 64 n-rows x 64 K each

    const int mbase = blockIdx.x * 128;   // token rows
    const int nbase = blockIdx.y * 64;    // output-feature rows
    const int tid  = threadIdx.x;
    const int lane = tid & 63;
    const int wv   = tid >> 6;
    const int wm   = wv >> 1, wn = wv & 1;   // wave grid: 2 (m) x 2 (n)
    const int lrow = lane & 15, quad = lane >> 4;
    const int l7   = lrow & 7;

    const u16* __restrict__ Wm[3] = { Wqb, Wkb, Wvb };

    const u16* ap[4];
#pragma unroll
    for (int t = 0; t < 4; ++t) {
        const int c = tid + t * 256;
        const int r = c >> 3;
        const int o = ((c & 7) ^ (r & 7)) * 8;
        ap[t] = &hsb[(size_t)(mbase + r) * HIDN + o];
    }
    const u16* bp[3][2];
#pragma unroll
    for (int z = 0; z < 3; ++z)
#pragma unroll
        for (int t = 0; t < 2; ++t) {
            const int c = tid + t * 256;
            const int r = c >> 3;
            const int o = ((c & 7) ^ (r & 7)) * 8;
            bp[z][t] = &Wm[z][(size_t)(nbase + r) * HIDN + o];
        }

    f32x4 accqk[2][2][4];   // [z][j][i]: C-row = n (quad*4+reg), C-col = token (lrow)
    f32x4 accv[4][2];       // [i][j]:    C-row = token,          C-col = n
#pragma unroll
    for (int z = 0; z < 2; ++z)
#pragma unroll
        for (int j = 0; j < 2; ++j)
#pragma unroll
            for (int i = 0; i < 4; ++i) accqk[z][j][i] = zf4();
#pragma unroll
    for (int i = 0; i < 4; ++i)
#pragma unroll
        for (int j = 0; j < 2; ++j) accv[i][j] = zf4();

    for (int k0 = 0; k0 < HIDN; k0 += 64) {
#pragma unroll
        for (int t = 0; t < 4; ++t)
            gld16(&As[(tid + t * 256) * 8], ap[t] + k0);
#pragma unroll
        for (int z = 0; z < 3; ++z)
#pragma unroll
            for (int t = 0; t < 2; ++t)
                gld16(&Bs[z][(tid + t * 256) * 8], bp[z][t] + k0);
        __syncthreads();   // drains vmcnt -> staged tiles visible

#pragma unroll
        for (int kk = 0; kk < 2; ++kk) {
            const int sc = ((kk * 4 + quad) ^ l7) * 8;   // swizzled 16B chunk
            bf16x8 hf[4], wf[3][2];
#pragma unroll
            for (int i = 0; i < 4; ++i)
                hf[i] = *(const bf16x8*)&As[(wm * 64 + i * 16 + lrow) * 64 + sc];
#pragma unroll
            for (int z = 0; z < 3; ++z)
#pragma unroll
                for (int j = 0; j < 2; ++j)
                    wf[z][j] = *(const bf16x8*)&Bs[z][(wn * 32 + j * 16 + lrow) * 64 + sc];
#pragma unroll
            for (int z = 0; z < 2; ++z)
#pragma unroll
                for (int j = 0; j < 2; ++j)
#pragma unroll
                    for (int i = 0; i < 4; ++i)
                        accqk[z][j][i] = mfma16(wf[z][j], hf[i], accqk[z][j][i]);
#pragma unroll
            for (int i = 0; i < 4; ++i)
#pragma unroll
                for (int j = 0; j < 2; ++j)
                    accv[i][j] = mfma16(hf[i], wf[2][j], accv[i][j]);
        }
        __syncthreads();   // protect LDS before next staging overwrite
    }

#pragma unroll
    for (int z = 0; z < 2; ++z) {
        u16* __restrict__ O = (z == 0) ? Qf : Kf;
        const float* __restrict__ bias = (z == 0) ? bq : bk;
#pragma unroll
        for (int j = 0; j < 2; ++j) {
#pragma unroll
            for (int i = 0; i < 4; ++i) {
                const int n0 = nbase + wn * 32 + j * 16 + quad * 4;
                const int m  = mbase + wm * 64 + i * 16 + lrow;
                const float4 b4 = *(const float4*)&bias[n0];
                u16x4 pk = { f2bf(accqk[z][j][i][0] + b4.x), f2bf(accqk[z][j][i][1] + b4.y),
                             f2bf(accqk[z][j][i][2] + b4.z), f2bf(accqk[z][j][i][3] + b4.w) };
                *(u16x4*)&O[(size_t)m * HIDN + n0] = pk;
            }
        }
    }
    {
        const int bb = mbase >> 11;           // batch (uniform per block)
        const int sb = mbase & 2047;
#pragma unroll
        for (int i = 0; i < 4; ++i) {
#pragma unroll
            for (int j = 0; j < 2; ++j) {
                const int n = nbase + wn * 32 + j * 16 + lrow;
                const int hh = n >> 6, d = n & 63;
                const float bs = bv[n];
                const int s0 = sb + wm * 64 + i * 16 + quad * 4;
                u16x4 pk = { f2bf(accv[i][j][0] + bs), f2bf(accv[i][j][1] + bs),
                             f2bf(accv[i][j][2] + bs), f2bf(accv[i][j][3] + bs) };
                *(u16x4*)&Vt[(((size_t)(bb * NHEAD + hh)) * HDIM + d) * S_LEN + s0] = pk;
            }
        }
    }
}

// ---------------------------------------------------------------------------
// Kernel 2: causal attention, SINGLE QK^T PASS.
// Block = (b, h, 16-row q-tile); 4 waves split the kt (64-col) tiles.
// Phase 1: QK^T -> exp2 -> accumulate l AND stash rounded-bf16 exp values in
// LDS expb[16][NC+8]. Phase 2 (after l reduce): NO K loads / QK MFMA / exp2 —
// read expb, scale by inv_l for the probs store, and feed PV MFMA directly
// (expb already has the A-operand lane=row layout; old pfl transpose deleted).
// ctx accumulated unnormalized, scaled by inv_l at epilogue (lane-local).
// Templated on NC: heavy half qt>=64 uses NC=2048 (66KB LDS, 2 blocks/CU),
// light half qt<64 uses NC=1024 (33KB, 4 blocks/CU). Heavy launched first.
// ctx combine overlays expb (stride-17), with a barrier before the overlay
// writes (columns are not wave-private).
// ---------------------------------------------------------------------------
template<int NC>
__global__ __launch_bounds__(256) void attn_1p(
    const u16* __restrict__ Qf,
    const u16* __restrict__ Kf,
    const u16* __restrict__ Vt,
    const float* __restrict__ amask,
    float* __restrict__ ctx,
    float* __restrict__ probs,
    int qt_base)
{
    constexpr int STR = NC + 8;          // u16 stride: 16B-aligned rows, 2-way banks on b128
    const int qt = qt_base - (int)blockIdx.x;   // heavy blocks dispatch first
    const int h  = blockIdx.y;
    const int b  = blockIdx.z;
    const int bh = b * NHEAD + h;
    const int tid  = threadIdx.x;
    const int lane = tid & 63;
    const int wv   = tid >> 6;
    const int lrow = lane & 15, quad = lane >> 4;
    const int row0 = qt * 16;
    const int dti  = qt >> 2;            // diagonal tile index
    const int nkt  = dti + 1;            // # of 64-col tiles touching causal region

    __shared__ __align__(16) u16 expb[16 * STR];   // bf16 exp buffer; combine overlay
    __shared__ float l_sh[4][16];

    // ---- zero-fill fully-masked probs tail (cols >= nkt*64) ----
    {
        const int tail  = nkt * 64;
        const int nt4   = (S_LEN - tail) >> 2;
        const int r  = tid >> 4;         // 16 threads per row
        const int c0 = tid & 15;
        const f32x4 zf = {0.f, 0.f, 0.f, 0.f};
        float* pr = &probs[((size_t)bh * S_LEN + row0 + r) * S_LEN + tail];
        for (int c4 = c0; c4 < nt4; c4 += 16)
            __builtin_nontemporal_store(zf, (f32x4*)&pr[c4 * 4]);
    }

    // ---- Q fragments ----
    const u16* qp = &Qf[((size_t)b * S_LEN + row0 + lrow) * HIDN + h * HDIM + quad * 8];
    const bf16x8 qa0 = *(const bf16x8*)qp;
    const bf16x8 qa1 = *(const bf16x8*)(qp + 32);

    const float* __restrict__ am = &amask[(size_t)b * S_LEN];
    const u16* __restrict__ kbase = &Kf[(size_t)b * S_LEN * HIDN + h * HDIM + quad * 8];

    // ---- phase 1: single QK^T pass -> exp -> l + bf16 stash ----
    float l_lane[4] = {0.f, 0.f, 0.f, 0.f};
    for (int kt = wv; kt < nkt; kt += 4) {
        f32x4 c[4];
#pragma unroll
        for (int cb = 0; cb < 4; ++cb) {
            const int col = kt * 64 + cb * 16 + lrow;
            const u16* kp = kbase + (size_t)col * HIDN;
            bf16x8 kb0 = *(const bf16x8*)kp;
            bf16x8 kb1 = *(const bf16x8*)(kp + 32);
            c[cb] = mfma16(qa0, kb0, zf4());
            c[cb] = mfma16(qa1, kb1, c[cb]);
        }
        if (kt == dti) {   // diagonal tile: causal compare
#pragma unroll
            for (int cb = 0; cb < 4; ++cb) {
                const int col = kt * 64 + cb * 16 + lrow;
                const float m8 = fmaf(am[col], LOG2E, NEG8_L2E);
#pragma unroll
                for (int reg = 0; reg < 4; ++reg) {
                    const int row = row0 + quad * 4 + reg;
                    const float e = (col <= row)
                        ? exp2f(fmaf(c[cb][reg], QS_L2E, m8)) : 0.f;
                    l_lane[reg] += e;
                    expb[(quad * 4 + reg) * STR + kt * 64 + cb * 16 + lrow] = f2bf(e);
                }
            }
        } else {           // interior: always unmasked
#pragma unroll
            for (int cb = 0; cb < 4; ++cb) {
                const int col = kt * 64 + cb * 16 + lrow;
                const float m8 = fmaf(am[col], LOG2E, NEG8_L2E);
#pragma unroll
                for (int reg = 0; reg < 4; ++reg) {
                    const float e = exp2f(fmaf(c[cb][reg], QS_L2E, m8));
                    l_lane[reg] += e;
                    expb[(quad * 4 + reg) * STR + kt * 64 + cb * 16 + lrow] = f2bf(e);
                }
            }
        }
    }
#pragma unroll
    for (int reg = 0; reg < 4; ++reg) {
#pragma unroll
        for (int off = 1; off < 16; off <<= 1)
            l_lane[reg] += __shfl_xor(l_lane[reg], off, 16);
    }
    if (lrow == 0) {
#pragma unroll
        for (int reg = 0; reg < 4; ++reg)
            l_sh[wv][quad * 4 + reg] = l_lane[reg];
    }
    __syncthreads();       // l complete + all expb writes visible
    float inv_l[4];
#pragma unroll
    for (int reg = 0; reg < 4; ++reg) {
        const int rr = quad * 4 + reg;
        inv_l[reg] = 1.f / (l_sh[0][rr] + l_sh[1][rr] + l_sh[2][rr] + l_sh[3][rr]);
    }

    // ---- phase 2: probs store + PV, all from expb ----
    f32x4 av[4];
#pragma unroll
    for (int db = 0; db < 4; ++db) av[db] = zf4();

    const u16* __restrict__ vbase = &Vt[(size_t)bh * HDIM * S_LEN + quad * 8];

    for (int kt = wv; kt < nkt; kt += 4) {
        // probs: row r = quad*4+it (inv_l[it] is lane-local), 256B segments
#pragma unroll
        for (int it = 0; it < 4; ++it) {
            const int r = quad * 4 + it;
            const float inv = inv_l[it];
            u16x4 p4 = *(const u16x4*)&expb[r * STR + kt * 64 + lrow * 4];
            f32x4 o;
#pragma unroll
            for (int j = 0; j < 4; ++j) o[j] = bf2f(p4[j]) * inv;
            __builtin_nontemporal_store(
                o, (f32x4*)&probs[((size_t)bh * S_LEN + row0 + r) * S_LEN + kt * 64 + lrow * 4]);
        }
        // PV: A-operand directly from expb (lane=row layout), unnormalized
        const bf16x8 pa0 = *(const bf16x8*)&expb[lrow * STR + kt * 64 + quad * 8];
        const bf16x8 pa1 = *(const bf16x8*)&expb[lrow * STR + kt * 64 + 32 + quad * 8];
#pragma unroll
        for (int db = 0; db < 4; ++db) {
            const u16* vp = vbase + (size_t)(db * 16 + lrow) * S_LEN + kt * 64;
            bf16x8 vb0 = *(const bf16x8*)vp;
            bf16x8 vb1 = *(const bf16x8*)(vp + 32);
            av[db] = mfma16(pa0, vb0, av[db]);
            av[db] = mfma16(pa1, vb1, av[db]);
        }
    }
    // normalize ctx rows (row = quad*4+reg -> inv_l[reg], lane-local)
#pragma unroll
    for (int db = 0; db < 4; ++db)
#pragma unroll
        for (int reg = 0; reg < 4; ++reg)
            av[db][reg] *= inv_l[reg];

    // ---- combine ctx partials across waves (overlay on expb) ----
    __syncthreads();       // all waves done reading expb
    float* cmb = (float*)expb;     // [4][64*17] = 17408 B <= both NC variants
#pragma unroll
    for (int db = 0; db < 4; ++db)
#pragma unroll
        for (int reg = 0; reg < 4; ++reg)
            cmb[wv * (64 * 17) + lane * 17 + db * 4 + reg] = av[db][reg];
    __syncthreads();
    // wave wv owns output cols d = wv*16 + lrow
#pragma unroll
    for (int reg = 0; reg < 4; ++reg) {
        const int sl = lane * 17 + wv * 4 + reg;
        const float s = cmb[0 * (64 * 17) + sl] + cmb[1 * (64 * 17) + sl]
                      + cmb[2 * (64 * 17) + sl] + cmb[3 * (64 * 17) + sl];
        __builtin_nontemporal_store(
            s, &ctx[((size_t)b * S_LEN + row0 + quad * 4 + reg) * HIDN + h * HDIM + wv * 16 + lrow]);
    }
}

// ---------------------------------------------------------------------------
extern "C" void kernel_launch(void* const* d_in, const int* in_sizes, int n_in,
                              void* d_out, int out_size, void* d_ws, size_t ws_size,
                              hipStream_t stream)
{
    const float* hs    = (const float*)d_in[0];
    const float* amask = (const float*)d_in[1];
    const float* Wq    = (const float*)d_in[2];
    const float* bq    = (const float*)d_in[3];
    const float* Wk    = (const float*)d_in[4];
    const float* bk    = (const float*)d_in[5];
    const float* Wv    = (const float*)d_in[6];
    const float* bv    = (const float*)d_in[7];

    float* out   = (float*)d_out;
    float* ctx   = out;                                     // [2,2048,1024]
    float* probs = out + (size_t)NBATCH * S_LEN * HIDN;     // [2,16,2048,2048]

    const size_t NTOK = (size_t)NBATCH * S_LEN;             // 4096
    u16* hsb = (u16*)d_ws;                                  // bf16 [4096][1024]
    u16* Wqb = hsb + NTOK * HIDN;                           // bf16 [1024][1024]
    u16* Wkb = Wqb + (size_t)HIDN * HIDN;
    u16* Wvb = Wkb + (size_t)HIDN * HIDN;
    u16* Qf  = Wvb + (size_t)HIDN * HIDN;                   // bf16 [4096][1024]
    u16* Kf  = Qf + NTOK * HIDN;
    u16* Vt  = Kf + NTOK * HIDN;                            // bf16 [B][NH][64][2048]

    const int nblk_cvt = (int)(NTOK * HIDN / 1024) + 3 * (HIDN * HIDN / 1024);  // 7168
    cvt_all<<<nblk_cvt, 256, 0, stream>>>(hs, Wq, Wk, Wv, hsb, Wqb, Wkb, Wvb);

    qkv_fused<<<dim3(32, 16), 256, 0, stream>>>(hsb, Wqb, Wkb, Wvb, bq, bk, bv, Qf, Kf, Vt);

    // heavy half first (qt 127..64, 66KB LDS), then light half (qt 63..0, 33KB)
    attn_1p<2048><<<dim3(64, 16, 2), 256, 0, stream>>>(Qf, Kf, Vt, amask, ctx, probs, 127);
    attn_1p<1024><<<dim3(64, 16, 2), 256, 0, stream>>>(Qf, Kf, Vt, amask, ctx, probs, 63);
}